// Round 1
// baseline (281.583 us; speedup 1.0000x reference)
//
#include <hip/hip_runtime.h>
#include <cstddef>
#include <cstdint>

#define B_DIM 8
#define L_DIM 2048
#define H_DIM 512
#define N_DIM 64
#define HN (H_DIM * N_DIM)          // 32768
#define BLH (B_DIM * L_DIM * H_DIM) // 8388608
#define M_DIM (B_DIM * L_DIM)       // 16384

typedef unsigned short u16;
typedef short bf16x8 __attribute__((ext_vector_type(8)));
typedef float floatx4 __attribute__((ext_vector_type(4)));

__device__ __forceinline__ float sigmoidf_(float v) {
    return 1.0f / (1.0f + __expf(-v));
}

// jax.nn.gelu default: approximate=True (tanh form)
__device__ __forceinline__ float gelu_tanh_(float x) {
    float x3 = x * x * x;
    float z = 0.7978845608028654f * fmaf(0.044715f, x3, x);
    float e = __expf(-2.0f * fabsf(z));
    float th = (1.0f - e) / (1.0f + e);
    th = copysignf(th, z);
    return 0.5f * x * (1.0f + th);
}

__device__ __forceinline__ u16 f2b(float f) {
    unsigned u = __float_as_uint(f);
    unsigned r = (u + 0x7fffu + ((u >> 16) & 1u)) >> 16;
    return (u16)r;
}
__device__ __forceinline__ float b2f(u16 u) {
    return __uint_as_float(((unsigned)u) << 16);
}
__device__ __forceinline__ void unpack2(unsigned u, float& a, float& b) {
    a = __uint_as_float(u << 16);
    b = __uint_as_float(u & 0xffff0000u);
}
__device__ __forceinline__ unsigned pack2(float a, float b) {
    return (unsigned)f2b(a) | ((unsigned)f2b(b) << 16);
}

// complex helpers
__device__ __forceinline__ void csq(float& r, float& i) {
    float nr = r * r - i * i;
    i = 2.0f * r * i;
    r = nr;
}

// ---------------------------------------------------------------------------
// 0) fp32 -> bf16 cast (weights)
// ---------------------------------------------------------------------------
__global__ __launch_bounds__(256) void cast_kernel(
    const float* __restrict__ src, u16* __restrict__ dst)
{
    int i = blockIdx.x * 256 + threadIdx.x;
    float4 v = *(const float4*)(src + (size_t)i * 4);
    uint2 p;
    p.x = pack2(v.x, v.y);
    p.y = pack2(v.z, v.w);
    *(uint2*)(dst + (size_t)i * 4) = p;
}

// ---------------------------------------------------------------------------
// 1) Per-(h,n) SSM params: w = exp(dt*A), Ct2 = 2*C*(exp(dt*A)-1)/A
// ---------------------------------------------------------------------------
__global__ __launch_bounds__(256) void precompute_kernel(
    const float* __restrict__ log_dt, const float* __restrict__ A_re,
    const float* __restrict__ A_im, const float* __restrict__ C_re,
    const float* __restrict__ C_im, float* __restrict__ P)
{
    int i = blockIdx.x * 256 + threadIdx.x;
    if (i >= HN) return;
    int h = i >> 6;
    float dt = expf(log_dt[h]);
    float Ar = A_re[i], Ai = A_im[i];
    float ar = dt * Ar, ai = dt * Ai;
    float e = expf(ar);
    float wr = e * cosf(ai);
    float wi = e * sinf(ai);
    float em1r = wr - 1.0f, em1i = wi;
    float inv = 1.0f / fmaf(Ar, Ar, Ai * Ai);
    float qr = fmaf(em1r, Ar, em1i * Ai) * inv;
    float qi = fmaf(em1i, Ar, -(em1r * Ai)) * inv;
    float Cr = C_re[i], Ci = C_im[i];
    float ctr = Cr * qr - Ci * qi;
    float cti = Cr * qi + Ci * qr;
    P[i]          = wr;
    P[HN + i]     = wi;
    P[2 * HN + i] = 2.0f * ctr;
    P[3 * HN + i] = 2.0f * cti;
}

// ---------------------------------------------------------------------------
// 1b) K table: K[h][tau] = sum_n Re(Ct2_n * w_n^tau), tau = 0..63
// ---------------------------------------------------------------------------
__global__ __launch_bounds__(256) void ktab_kernel(
    const float* __restrict__ P, float* __restrict__ Ktab)
{
    int wv = threadIdx.x >> 6, lane = threadIdx.x & 63;
    int h = blockIdx.x * 4 + wv;
    int pidx = (h << 6) + lane;
    float wr = P[pidx], wi = P[HN + pidx];
    float c2r = P[2 * HN + pidx], c2i = P[3 * HN + pidx];
    float pr = 1.0f, pi = 0.0f;
    for (int tau = 0; tau < 64; ++tau) {
        float term = c2r * pr - c2i * pi;
        #pragma unroll
        for (int m = 32; m > 0; m >>= 1) term += __shfl_xor(term, m, 64);
        if (lane == 0) Ktab[(h << 6) + tau] = term;
        float nr = pr * wr - pi * wi, ni = pr * wi + pi * wr;
        pr = nr; pi = ni;
    }
}

// ---------------------------------------------------------------------------
// 1c) Toeplitz fill: Toep_bf[h][t][j] = (j<=t) ? bf16(K[h][t-j]) : 0
// ---------------------------------------------------------------------------
__global__ __launch_bounds__(256) void toepfill_kernel(
    const float* __restrict__ Ktab, u16* __restrict__ Toep_bf)
{
    int idx = blockIdx.x * 256 + threadIdx.x;   // 512*4096
    int h = idx >> 12;
    int rem = idx & 4095;
    int tt = rem >> 6, j = rem & 63;
    u16 v = 0;
    if (j <= tt) v = f2b(Ktab[(h << 6) + (tt - j)]);
    Toep_bf[idx] = v;
}

// ---------------------------------------------------------------------------
// 2) Transpose x (B,L,H) fp32 -> XT (B,H,L) bf16
// ---------------------------------------------------------------------------
__global__ __launch_bounds__(256) void xtrans_kernel(
    const float* __restrict__ x, u16* __restrict__ XT)
{
    __shared__ float tile[32][33];
    int b  = blockIdx.z;
    int l0 = blockIdx.x * 32;
    int h0 = blockIdx.y * 32;
    int tx = threadIdx.x & 31;
    int ty = threadIdx.x >> 5;
    #pragma unroll
    for (int r = 0; r < 4; ++r)
        tile[ty + r * 8][tx] = x[((size_t)b * L_DIM + l0 + ty + r * 8) * H_DIM + h0 + tx];
    __syncthreads();
    #pragma unroll
    for (int r = 0; r < 4; ++r)
        XT[((size_t)b * H_DIM + h0 + ty + r * 8) * L_DIM + l0 + tx] = f2b(tile[tx][ty + r * 8]);
}

// ---------------------------------------------------------------------------
// 3) Chunked SSM via MFMA. One workgroup = (h, half of b). T=64, 32 chunks.
//    Phase A: S_local(128x128) = E(128x64) @ U(cols)  [MFMA]
//    Phase B: 32-step chunk recurrence (256 serial lanes)
//    Phase C: Y(64x128) = Toep(64x64)@U + V(64x128)@S_in [MFMA] + D*u + GELU
// ---------------------------------------------------------------------------
__global__ __launch_bounds__(256) void ssm_chunk_kernel(
    const u16* __restrict__ XT, const float* __restrict__ P,
    const u16* __restrict__ Toep_bf, const float* __restrict__ D_skip,
    u16* __restrict__ YT)
{
    __shared__ u16 U[128 * 72];      // [ncol][j], pad 72
    __shared__ u16 S[128 * 136];     // [ncol][2n], pad 136
    __shared__ u16 EVT[13312];       // union: E[128*72]=9216 | Toep[64*72]=4608 + V[64*136]=8704
    u16* E  = EVT;
    u16* Tp = EVT;
    u16* V  = EVT + 4608;

    const int h    = blockIdx.x;
    const int b0   = blockIdx.y * 4;
    const int t    = threadIdx.x;
    const int lane = t & 63;
    const int wv   = t >> 6;
    const int lm   = lane & 15, lq = lane >> 4;

    const int pidx = (h << 6) + lane;
    const float wr  = P[pidx],          wi  = P[HN + pidx];
    const float c2r = P[2 * HN + pidx], c2i = P[3 * HN + pidx];

    // stage U: 128 rows x 64 bf16, 16B chunks (coalesced), padded LDS rows
    #pragma unroll
    for (int r = 0; r < 4; ++r) {
        int idx = t + r * 256;
        int row = idx >> 3, ch = idx & 7;
        const u16* gp = XT + (((size_t)(b0 + (row >> 5)) * H_DIM + h) << 11)
                           + ((row & 31) << 6) + (ch << 3);
        *(uint4*)&U[row * 72 + ch * 8] = *(const uint4*)gp;
    }

    // base power w^(16*wv) for this wave
    float bwr, bwi;
    {
        float g16r = wr, g16i = wi;
        csq(g16r, g16i); csq(g16r, g16i); csq(g16r, g16i); csq(g16r, g16i); // w^16
        if (wv == 0)      { bwr = 1.0f; bwi = 0.0f; }
        else if (wv == 1) { bwr = g16r; bwi = g16i; }
        else if (wv == 2) { bwr = g16r; bwi = g16i; csq(bwr, bwi); }
        else {
            float g32r = g16r, g32i = g16i; csq(g32r, g32i);
            bwr = g32r * g16r - g32i * g16i;
            bwi = g32r * g16i + g32i * g16r;
        }
    }

    // fill E: E[2n][j]=Re(w^(63-j)), E[2n+1][j]=Im(w^(63-j)); wave wv covers k=16wv..16wv+15
    {
        float pr = bwr, pi = bwi;
        #pragma unroll
        for (int jk = 0; jk < 16; ++jk) {
            int k = (wv << 4) + jk;
            int j = 63 - k;
            E[(2 * lane) * 72 + j]     = f2b(pr);
            E[(2 * lane + 1) * 72 + j] = f2b(pi);
            float nr = pr * wr - pi * wi, ni = pr * wi + pi * wr;
            pr = nr; pi = ni;
        }
    }
    __syncthreads();

    // Phase A: acc[m][ncol], m = state index (2n interleaved), ncol = (bloc,c)
    {
        const int wm = wv >> 1, wn = wv & 1;
        floatx4 acc[4][4] = {};
        #pragma unroll
        for (int ks = 0; ks < 2; ++ks) {
            bf16x8 af[4], bfv[4];
            #pragma unroll
            for (int i = 0; i < 4; ++i)
                af[i] = *(const bf16x8*)&E[(wm * 64 + i * 16 + lm) * 72 + ks * 32 + lq * 8];
            #pragma unroll
            for (int j = 0; j < 4; ++j)
                bfv[j] = *(const bf16x8*)&U[(wn * 64 + j * 16 + lm) * 72 + ks * 32 + lq * 8];
            #pragma unroll
            for (int i = 0; i < 4; ++i) {
                #pragma unroll
                for (int j = 0; j < 4; ++j)
                    acc[i][j] = __builtin_amdgcn_mfma_f32_16x16x32_bf16(af[i], bfv[j], acc[i][j], 0, 0, 0);
            }
        }
        #pragma unroll
        for (int i = 0; i < 4; ++i) {
            #pragma unroll
            for (int j = 0; j < 4; ++j) {
                int ncol = wn * 64 + j * 16 + lm;
                int m0   = wm * 64 + i * 16 + lq * 4;
                u16 pk[4];
                #pragma unroll
                for (int r = 0; r < 4; ++r) pk[r] = f2b(acc[i][j][r]);
                *(uint2*)&S[ncol * 136 + m0] = *(uint2*)pk;
            }
        }
    }
    __syncthreads();   // E reads + S_local writes complete

    // fill V (overwrites E region, disjoint from Toep) + stage Toep + chunk scan
    {
        // V: wave wv covers k = 16wv+1 .. 16wv+16; V[t=k-1][2n]=Re(Ct2 w^k), [2n+1]=-Im
        float pr = bwr, pi = bwi;
        {   // advance to k = 16wv+1
            float nr = pr * wr - pi * wi, ni = pr * wi + pi * wr;
            pr = nr; pi = ni;
        }
        #pragma unroll
        for (int jk = 1; jk <= 16; ++jk) {
            int tr = (wv << 4) + jk - 1;
            float qr = c2r * pr - c2i * pi;
            float qi = c2r * pi + c2i * pr;
            V[tr * 136 + 2 * lane]     = f2b(qr);
            V[tr * 136 + 2 * lane + 1] = f2b(-qi);
            float nr = pr * wr - pi * wi, ni = pr * wi + pi * wr;
            pr = nr; pi = ni;
        }
        // stage Toeplitz 64x64 -> [64][72]
        #pragma unroll
        for (int r = 0; r < 2; ++r) {
            int idx = t + r * 256;
            int row = idx >> 3, ch = idx & 7;
            *(uint4*)&Tp[row * 72 + ch * 8] =
                *(const uint4*)&Toep_bf[((size_t)h << 12) + (row << 6) + (ch << 3)];
        }
        // chunk scan: thread = chain (bloc = wv, n = lane); in-place S_local -> S_in
        float wTr = wr, wTi = wi;
        csq(wTr, wTi); csq(wTr, wTi); csq(wTr, wTi);
        csq(wTr, wTi); csq(wTr, wTi); csq(wTr, wTi);   // w^64
        float Sr = 0.0f, Si = 0.0f;
        const int n2 = lane * 2;
        for (int c = 0; c < 32; ++c) {
            int base = (wv * 32 + c) * 136 + n2;
            unsigned lv = *(unsigned*)&S[base];
            float lr, li;
            unpack2(lv, lr, li);
            *(unsigned*)&S[base] = pack2(Sr, Si);
            float nSr = wTr * Sr - wTi * Si + lr;
            Si = wTr * Si + wTi * Sr + li;
            Sr = nSr;
        }
    }
    __syncthreads();

    // Phase C: Y[t][ncol] = Toep@U + V@S_in; epilogue D*u + GELU -> YT (b,h,l)
    {
        const float Dh = D_skip[h];
        floatx4 acc[4][2] = {};
        #pragma unroll
        for (int ks = 0; ks < 6; ++ks) {
            bf16x8 af[4], bfv[2];
            if (ks < 2) {
                #pragma unroll
                for (int i = 0; i < 4; ++i)
                    af[i] = *(const bf16x8*)&Tp[(i * 16 + lm) * 72 + ks * 32 + lq * 8];
                #pragma unroll
                for (int j = 0; j < 2; ++j)
                    bfv[j] = *(const bf16x8*)&U[(wv * 32 + j * 16 + lm) * 72 + ks * 32 + lq * 8];
            } else {
                #pragma unroll
                for (int i = 0; i < 4; ++i)
                    af[i] = *(const bf16x8*)&V[(i * 16 + lm) * 136 + (ks - 2) * 32 + lq * 8];
                #pragma unroll
                for (int j = 0; j < 2; ++j)
                    bfv[j] = *(const bf16x8*)&S[(wv * 32 + j * 16 + lm) * 136 + (ks - 2) * 32 + lq * 8];
            }
            #pragma unroll
            for (int i = 0; i < 4; ++i) {
                #pragma unroll
                for (int j = 0; j < 2; ++j)
                    acc[i][j] = __builtin_amdgcn_mfma_f32_16x16x32_bf16(af[i], bfv[j], acc[i][j], 0, 0, 0);
            }
        }
        #pragma unroll
        for (int j = 0; j < 2; ++j) {
            int ncol = wv * 32 + j * 16 + lm;
            int bloc = ncol >> 5, c = ncol & 31;
            size_t gbase = (((size_t)(b0 + bloc) * H_DIM + h) << 11) + (c << 6);
            #pragma unroll
            for (int i = 0; i < 4; ++i) {
                int t0 = i * 16 + lq * 4;
                u16 upk[4];
                *(uint2*)upk = *(const uint2*)&U[ncol * 72 + t0];
                u16 opk[4];
                #pragma unroll
                for (int r = 0; r < 4; ++r) {
                    float uvv = b2f(upk[r]);
                    float yv = gelu_tanh_(fmaf(Dh, uvv, acc[i][j][r]));
                    opk[r] = f2b(yv);
                }
                *(uint2*)&YT[gbase + t0] = *(uint2*)opk;
            }
        }
    }
}

// ---------------------------------------------------------------------------
// 4) Transpose YT (B,H,L) bf16 -> Y (B,L,H) bf16
// ---------------------------------------------------------------------------
__global__ __launch_bounds__(256) void ytrans_kernel(
    const u16* __restrict__ YT, u16* __restrict__ Y)
{
    __shared__ u16 tile[32][33];
    int b  = blockIdx.z;
    int l0 = blockIdx.x * 32;
    int h0 = blockIdx.y * 32;
    int tx = threadIdx.x & 31;
    int ty = threadIdx.x >> 5;
    #pragma unroll
    for (int r = 0; r < 4; ++r)
        tile[ty + r * 8][tx] = YT[((size_t)b * H_DIM + h0 + ty + r * 8) * L_DIM + l0 + tx];
    __syncthreads();
    #pragma unroll
    for (int r = 0; r < 4; ++r)
        Y[((size_t)b * L_DIM + l0 + ty + r * 8) * H_DIM + h0 + tx] = tile[tx][ty + r * 8];
}

// ---------------------------------------------------------------------------
// stage a 128x32 bf16 tile (row-major, ld=512) into LDS via global_load_lds
// ---------------------------------------------------------------------------
__device__ __forceinline__ void stage_tile_128x32(
    const u16* __restrict__ g, u16* lds, int row0, int k0)
{
    const int t = threadIdx.x;
    #pragma unroll
    for (int r = 0; r < 2; ++r) {
        int row = (t >> 2) + r * 64;
        int col = (t & 3) * 8;
        const u16* gp = g + (size_t)(row0 + row) * 512 + k0 + col;
        __builtin_amdgcn_global_load_lds(
            (const __attribute__((address_space(1))) unsigned int*)gp,
            (__attribute__((address_space(3))) unsigned int*)(lds + (size_t)t * 8 + (size_t)r * 2048),
            16, 0, 0);
    }
}

// ---------------------------------------------------------------------------
// 5) GEMM1 + GLU + residual (dual-B), double-buffered prefetch (T3 2-phase):
//    STAGE(next) -> compute(cur) -> vmcnt(0)+barrier. Load latency hides
//    under the MFMA cluster instead of being drained cold each K-step.
// ---------------------------------------------------------------------------
__global__ __launch_bounds__(256) void gemm1_glu_kernel(
    const u16* __restrict__ A, const u16* __restrict__ Wo,
    const float* __restrict__ bo, const float* __restrict__ x,
    u16* __restrict__ out)
{
    __shared__ u16 As[2][128 * 32];
    __shared__ u16 Ba[2][128 * 32];
    __shared__ u16 Bg[2][128 * 32];
    const int t    = threadIdx.x;
    const int lane = t & 63;
    const int wv   = t >> 6;
    const int wm   = wv >> 1, wn = wv & 1;
    const int lm   = lane & 15, lq = lane >> 4;
    const int m0   = blockIdx.x * 128, n0 = blockIdx.y * 128;
    floatx4 accA[4][4] = {};
    floatx4 accG[4][4] = {};

    // prologue: stage k=0 into buffer 0, full drain
    stage_tile_128x32(A, As[0], m0, 0);
    stage_tile_128x32(Wo, Ba[0], n0, 0);
    stage_tile_128x32(Wo, Bg[0], 512 + n0, 0);
    asm volatile("s_waitcnt vmcnt(0)" ::: "memory");
    __builtin_amdgcn_s_barrier();
    asm volatile("" ::: "memory");

    int cur = 0;
    for (int k0 = 0; k0 < 512; k0 += 32) {
        const int nx = cur ^ 1;
        const bool more = (k0 + 32 < 512);
        if (more) {
            stage_tile_128x32(A, As[nx], m0, k0 + 32);
            stage_tile_128x32(Wo, Ba[nx], n0, k0 + 32);
            stage_tile_128x32(Wo, Bg[nx], 512 + n0, k0 + 32);
        }
        bf16x8 af[4], ba[4], bg[4];
        #pragma unroll
        for (int i = 0; i < 4; ++i)
            af[i] = *(const bf16x8*)&As[cur][(wm * 64 + i * 16 + lm) * 32 + lq * 8];
        #pragma unroll
        for (int j = 0; j < 4; ++j) {
            ba[j] = *(const bf16x8*)&Ba[cur][(wn * 64 + j * 16 + lm) * 32 + lq * 8];
            bg[j] = *(const bf16x8*)&Bg[cur][(wn * 64 + j * 16 + lm) * 32 + lq * 8];
        }
        #pragma unroll
        for (int i = 0; i < 4; ++i) {
            #pragma unroll
            for (int j = 0; j < 4; ++j) {
                accA[i][j] = __builtin_amdgcn_mfma_f32_16x16x32_bf16(af[i], ba[j], accA[i][j], 0, 0, 0);
                accG[i][j] = __builtin_amdgcn_mfma_f32_16x16x32_bf16(af[i], bg[j], accG[i][j], 0, 0, 0);
            }
        }
        if (more) {
            asm volatile("" ::: "memory");
            asm volatile("s_waitcnt vmcnt(0)" ::: "memory");
            __builtin_amdgcn_s_barrier();
            asm volatile("" ::: "memory");
        }
        cur = nx;
    }
    #pragma unroll
    for (int j = 0; j < 4; ++j) {
        int n = n0 + wn * 64 + j * 16 + lm;
        float bav = bo[n], bgv = bo[512 + n];
        #pragma unroll
        for (int i = 0; i < 4; ++i) {
            #pragma unroll
            for (int r = 0; r < 4; ++r) {
                int m = m0 + wm * 64 + i * 16 + lq * 4 + r;
                float av = accA[i][j][r] + bav;
                float gv = accG[i][j][r] + bgv;
                float xv = x[(size_t)m * 512 + n];
                out[(size_t)m * 512 + n] = f2b(fmaf(av, sigmoidf_(gv), xv));
            }
        }
    }
}

// ---------------------------------------------------------------------------
// 6/7) MFMA GEMM: C_bf16 = act(A[M,512]·Bw[512,512]^T + bias). EPI: 1=relu
//      Same double-buffered prefetch structure.
// ---------------------------------------------------------------------------
template<int EPI>
__global__ __launch_bounds__(256) void gemm_bt_bf_kernel(
    const u16* __restrict__ A, const u16* __restrict__ Bw,
    const float* __restrict__ bias, u16* __restrict__ C)
{
    __shared__ u16 As[2][128 * 32];
    __shared__ u16 Bs[2][128 * 32];
    const int t    = threadIdx.x;
    const int lane = t & 63;
    const int wv   = t >> 6;
    const int wm   = wv >> 1, wn = wv & 1;
    const int lm   = lane & 15, lq = lane >> 4;
    const int m0   = blockIdx.x * 128, n0 = blockIdx.y * 128;
    floatx4 acc[4][4] = {};

    stage_tile_128x32(A, As[0], m0, 0);
    stage_tile_128x32(Bw, Bs[0], n0, 0);
    asm volatile("s_waitcnt vmcnt(0)" ::: "memory");
    __builtin_amdgcn_s_barrier();
    asm volatile("" ::: "memory");

    int cur = 0;
    for (int k0 = 0; k0 < 512; k0 += 32) {
        const int nx = cur ^ 1;
        const bool more = (k0 + 32 < 512);
        if (more) {
            stage_tile_128x32(A, As[nx], m0, k0 + 32);
            stage_tile_128x32(Bw, Bs[nx], n0, k0 + 32);
        }
        bf16x8 af[4], bfr[4];
        #pragma unroll
        for (int i = 0; i < 4; ++i)
            af[i] = *(const bf16x8*)&As[cur][(wm * 64 + i * 16 + lm) * 32 + lq * 8];
        #pragma unroll
        for (int j = 0; j < 4; ++j)
            bfr[j] = *(const bf16x8*)&Bs[cur][(wn * 64 + j * 16 + lm) * 32 + lq * 8];
        #pragma unroll
        for (int i = 0; i < 4; ++i) {
            #pragma unroll
            for (int j = 0; j < 4; ++j)
                acc[i][j] = __builtin_amdgcn_mfma_f32_16x16x32_bf16(af[i], bfr[j], acc[i][j], 0, 0, 0);
        }
        if (more) {
            asm volatile("" ::: "memory");
            asm volatile("s_waitcnt vmcnt(0)" ::: "memory");
            __builtin_amdgcn_s_barrier();
            asm volatile("" ::: "memory");
        }
        cur = nx;
    }
    #pragma unroll
    for (int j = 0; j < 4; ++j) {
        int n = n0 + wn * 64 + j * 16 + lm;
        float bv = bias[n];
        #pragma unroll
        for (int i = 0; i < 4; ++i) {
            #pragma unroll
            for (int r = 0; r < 4; ++r) {
                int m = m0 + wm * 64 + i * 16 + lq * 4 + r;
                float v = acc[i][j][r] + bv;
                if (EPI == 1) v = fmaxf(v, 0.0f);
                C[(size_t)m * 512 + n] = f2b(v);
            }
        }
    }
}

// ---------------------------------------------------------------------------
// 8) LayerNorm over H=512; bf16 in, optional bf16 residual; out bf16 or fp32
// ---------------------------------------------------------------------------
template<bool HASRES, bool F32OUT>
__global__ __launch_bounds__(256) void ln_bf_kernel(
    const u16* __restrict__ in, const u16* __restrict__ res,
    const float* __restrict__ gamma, const float* __restrict__ beta,
    u16* __restrict__ outb, float* __restrict__ outf)
{
    int w    = threadIdx.x >> 6;
    int lane = threadIdx.x & 63;
    size_t row  = (size_t)blockIdx.x * 4 + w;
    size_t base = row * 512 + lane * 8;
    uint4 raw = *(const uint4*)(in + base);
    float v[8];
    unpack2(raw.x, v[0], v[1]); unpack2(raw.y, v[2], v[3]);
    unpack2(raw.z, v[4], v[5]); unpack2(raw.w, v[6], v[7]);
    if (HASRES) {
        uint4 rr = *(const uint4*)(res + base);
        float rv[8];
        unpack2(rr.x, rv[0], rv[1]); unpack2(rr.y, rv[2], rv[3]);
        unpack2(rr.z, rv[4], rv[5]); unpack2(rr.w, rv[6], rv[7]);
        #pragma unroll
        for (int i = 0; i < 8; ++i) v[i] += rv[i];
    }
    float s = 0.0f, sq = 0.0f;
    #pragma unroll
    for (int i = 0; i < 8; ++i) { s += v[i]; sq = fmaf(v[i], v[i], sq); }
    #pragma unroll
    for (int m = 32; m > 0; m >>= 1) {
        s  += __shfl_xor(s, m, 64);
        sq += __shfl_xor(sq, m, 64);
    }
    float mu  = s * (1.0f / 512.0f);
    float var = sq * (1.0f / 512.0f) - mu * mu;
    float rs  = rsqrtf(var + 1e-5f);
    float g[8], bt[8];
    *(float4*)&g[0]  = *(const float4*)(gamma + lane * 8);
    *(float4*)&g[4]  = *(const float4*)(gamma + lane * 8 + 4);
    *(float4*)&bt[0] = *(const float4*)(beta + lane * 8);
    *(float4*)&bt[4] = *(const float4*)(beta + lane * 8 + 4);
    float o[8];
    #pragma unroll
    for (int i = 0; i < 8; ++i)
        o[i] = fmaf((v[i] - mu) * rs, g[i], bt[i]);
    if (F32OUT) {
        *(float4*)(outf + base)     = *(float4*)&o[0];
        *(float4*)(outf + base + 4) = *(float4*)&o[4];
    } else {
        uint4 p;
        p.x = pack2(o[0], o[1]); p.y = pack2(o[2], o[3]);
        p.z = pack2(o[4], o[5]); p.w = pack2(o[6], o[7]);
        *(uint4*)(outb + base) = p;
    }
}

// ---------------------------------------------------------------------------
extern "C" void kernel_launch(void* const* d_in, const int* in_sizes, int n_in,
                              void* d_out, int out_size, void* d_ws, size_t ws_size,
                              hipStream_t stream)
{
    (void)in_sizes; (void)n_in; (void)out_size; (void)ws_size;
    const float* x      = (const float*)d_in[0];
    const float* log_dt = (const float*)d_in[1];
    const float* A_re   = (const float*)d_in[2];
    const float* A_im   = (const float*)d_in[3];
    const float* C_re   = (const float*)d_in[4];
    const float* C_im   = (const float*)d_in[5];
    const float* D_skip = (const float*)d_in[6];
    const float* W_out  = (const float*)d_in[7];
    const float* b_out  = (const float*)d_in[8];
    const float* g1     = (const float*)d_in[9];
    const float* beta1  = (const float*)d_in[10];
    const float* g2     = (const float*)d_in[11];
    const float* beta2  = (const float*)d_in[12];
    const float* W1     = (const float*)d_in[13];
    const float* bc1    = (const float*)d_in[14];
    const float* W2     = (const float*)d_in[15];
    const float* bc2    = (const float*)d_in[16];
    float* out = (float*)d_out;

    // workspace: P 512K | Ktab 128K | Toep_bf 4M | weights 2M | r1/r2/r3 bf16 BLH
    char*  wsb    = (char*)d_ws;
    float* P      = (float*)wsb;
    float* Ktab   = (float*)(wsb + 4 * HN * 4);
    u16*   Toep   = (u16*)(wsb + 4 * HN * 4 + 512 * 64 * 4);
    u16*   Wobf   = Toep + 512 * 4096;
    u16*   W1bf   = Wobf + 1024 * 512;
    u16*   W2bf   = W1bf + 512 * 512;
    u16*   r1     = W2bf + 512 * 512;   // XT -> x1n_bf
    u16*   r2     = r1 + BLH;           // YT -> x1pre_bf -> y2_bf
    u16*   r3     = r2 + BLH;           // Y  -> h1_bf

    cast_kernel<<<512, 256, 0, stream>>>(W_out, Wobf);
    cast_kernel<<<256, 256, 0, stream>>>(W1, W1bf);
    cast_kernel<<<256, 256, 0, stream>>>(W2, W2bf);
    precompute_kernel<<<HN / 256, 256, 0, stream>>>(log_dt, A_re, A_im, C_re, C_im, P);
    ktab_kernel<<<128, 256, 0, stream>>>(P, Ktab);
    toepfill_kernel<<<8192, 256, 0, stream>>>(Ktab, Toep);
    xtrans_kernel<<<dim3(L_DIM / 32, H_DIM / 32, B_DIM), 256, 0, stream>>>(x, r1);
    ssm_chunk_kernel<<<dim3(H_DIM, 2), 256, 0, stream>>>(r1, P, Toep, D_skip, r2);
    ytrans_kernel<<<dim3(L_DIM / 32, H_DIM / 32, B_DIM), 256, 0, stream>>>(r2, r3);
    gemm1_glu_kernel<<<dim3(M_DIM / 128, 4), 256, 0, stream>>>(r3, Wobf, b_out, x, r2);
    ln_bf_kernel<false, false><<<M_DIM / 4, 256, 0, stream>>>(r2, nullptr, g1, beta1, r1, nullptr);
    gemm_bt_bf_kernel<1><<<dim3(M_DIM / 128, 4), 256, 0, stream>>>(r1, W1bf, bc1, r3);
    gemm_bt_bf_kernel<0><<<dim3(M_DIM / 128, 4), 256, 0, stream>>>(r3, W2bf, bc2, r2);
    ln_bf_kernel<true, true><<<M_DIM / 4, 256, 0, stream>>>(r2, r1, g2, beta2, nullptr, out);
}

// Round 2
// 253.842 us; speedup vs baseline: 1.1093x; 1.1093x over previous
//
#include <hip/hip_runtime.h>
#include <cstddef>
#include <cstdint>

#define B_DIM 8
#define L_DIM 2048
#define H_DIM 512
#define N_DIM 64
#define HN (H_DIM * N_DIM)          // 32768
#define BLH (B_DIM * L_DIM * H_DIM) // 8388608
#define M_DIM (B_DIM * L_DIM)       // 16384

typedef unsigned short u16;
typedef short bf16x8 __attribute__((ext_vector_type(8)));
typedef float floatx4 __attribute__((ext_vector_type(4)));

__device__ __forceinline__ float sigmoidf_(float v) {
    return 1.0f / (1.0f + __expf(-v));
}

// jax.nn.gelu default: approximate=True (tanh form)
__device__ __forceinline__ float gelu_tanh_(float x) {
    float x3 = x * x * x;
    float z = 0.7978845608028654f * fmaf(0.044715f, x3, x);
    float e = __expf(-2.0f * fabsf(z));
    float th = (1.0f - e) / (1.0f + e);
    th = copysignf(th, z);
    return 0.5f * x * (1.0f + th);
}

__device__ __forceinline__ u16 f2b(float f) {
    unsigned u = __float_as_uint(f);
    unsigned r = (u + 0x7fffu + ((u >> 16) & 1u)) >> 16;
    return (u16)r;
}
__device__ __forceinline__ float b2f(u16 u) {
    return __uint_as_float(((unsigned)u) << 16);
}
__device__ __forceinline__ void unpack2(unsigned u, float& a, float& b) {
    a = __uint_as_float(u << 16);
    b = __uint_as_float(u & 0xffff0000u);
}
__device__ __forceinline__ unsigned pack2(float a, float b) {
    return (unsigned)f2b(a) | ((unsigned)f2b(b) << 16);
}

// complex helpers
__device__ __forceinline__ void csq(float& r, float& i) {
    float nr = r * r - i * i;
    i = 2.0f * r * i;
    r = nr;
}

// ---------------------------------------------------------------------------
// 0) fp32 -> bf16 cast (weights)
// ---------------------------------------------------------------------------
__global__ __launch_bounds__(256) void cast_kernel(
    const float* __restrict__ src, u16* __restrict__ dst)
{
    int i = blockIdx.x * 256 + threadIdx.x;
    float4 v = *(const float4*)(src + (size_t)i * 4);
    uint2 p;
    p.x = pack2(v.x, v.y);
    p.y = pack2(v.z, v.w);
    *(uint2*)(dst + (size_t)i * 4) = p;
}

// ---------------------------------------------------------------------------
// 1) Per-(h,n) SSM params: w = exp(dt*A), Ct2 = 2*C*(exp(dt*A)-1)/A
// ---------------------------------------------------------------------------
__global__ __launch_bounds__(256) void precompute_kernel(
    const float* __restrict__ log_dt, const float* __restrict__ A_re,
    const float* __restrict__ A_im, const float* __restrict__ C_re,
    const float* __restrict__ C_im, float* __restrict__ P)
{
    int i = blockIdx.x * 256 + threadIdx.x;
    if (i >= HN) return;
    int h = i >> 6;
    float dt = expf(log_dt[h]);
    float Ar = A_re[i], Ai = A_im[i];
    float ar = dt * Ar, ai = dt * Ai;
    float e = expf(ar);
    float wr = e * cosf(ai);
    float wi = e * sinf(ai);
    float em1r = wr - 1.0f, em1i = wi;
    float inv = 1.0f / fmaf(Ar, Ar, Ai * Ai);
    float qr = fmaf(em1r, Ar, em1i * Ai) * inv;
    float qi = fmaf(em1i, Ar, -(em1r * Ai)) * inv;
    float Cr = C_re[i], Ci = C_im[i];
    float ctr = Cr * qr - Ci * qi;
    float cti = Cr * qi + Ci * qr;
    P[i]          = wr;
    P[HN + i]     = wi;
    P[2 * HN + i] = 2.0f * ctr;
    P[3 * HN + i] = 2.0f * cti;
}

// ---------------------------------------------------------------------------
// 1b) K table: K[h][tau] = sum_n Re(Ct2_n * w_n^tau), tau = 0..63
// ---------------------------------------------------------------------------
__global__ __launch_bounds__(256) void ktab_kernel(
    const float* __restrict__ P, float* __restrict__ Ktab)
{
    int wv = threadIdx.x >> 6, lane = threadIdx.x & 63;
    int h = blockIdx.x * 4 + wv;
    int pidx = (h << 6) + lane;
    float wr = P[pidx], wi = P[HN + pidx];
    float c2r = P[2 * HN + pidx], c2i = P[3 * HN + pidx];
    float pr = 1.0f, pi = 0.0f;
    for (int tau = 0; tau < 64; ++tau) {
        float term = c2r * pr - c2i * pi;
        #pragma unroll
        for (int m = 32; m > 0; m >>= 1) term += __shfl_xor(term, m, 64);
        if (lane == 0) Ktab[(h << 6) + tau] = term;
        float nr = pr * wr - pi * wi, ni = pr * wi + pi * wr;
        pr = nr; pi = ni;
    }
}

// ---------------------------------------------------------------------------
// 1c) Toeplitz fill: Toep_bf[h][t][j] = (j<=t) ? bf16(K[h][t-j]) : 0
// ---------------------------------------------------------------------------
__global__ __launch_bounds__(256) void toepfill_kernel(
    const float* __restrict__ Ktab, u16* __restrict__ Toep_bf)
{
    int idx = blockIdx.x * 256 + threadIdx.x;   // 512*4096
    int h = idx >> 12;
    int rem = idx & 4095;
    int tt = rem >> 6, j = rem & 63;
    u16 v = 0;
    if (j <= tt) v = f2b(Ktab[(h << 6) + (tt - j)]);
    Toep_bf[idx] = v;
}

// ---------------------------------------------------------------------------
// 2) Transpose x (B,L,H) fp32 -> XT (B,H,L) bf16
// ---------------------------------------------------------------------------
__global__ __launch_bounds__(256) void xtrans_kernel(
    const float* __restrict__ x, u16* __restrict__ XT)
{
    __shared__ float tile[32][33];
    int b  = blockIdx.z;
    int l0 = blockIdx.x * 32;
    int h0 = blockIdx.y * 32;
    int tx = threadIdx.x & 31;
    int ty = threadIdx.x >> 5;
    #pragma unroll
    for (int r = 0; r < 4; ++r)
        tile[ty + r * 8][tx] = x[((size_t)b * L_DIM + l0 + ty + r * 8) * H_DIM + h0 + tx];
    __syncthreads();
    #pragma unroll
    for (int r = 0; r < 4; ++r)
        XT[((size_t)b * H_DIM + h0 + ty + r * 8) * L_DIM + l0 + tx] = f2b(tile[tx][ty + r * 8]);
}

// ---------------------------------------------------------------------------
// 3) Chunked SSM via MFMA. One workgroup = (h, half of b). T=64, 32 chunks.
//    Phase A: S_local(128x128) = E(128x64) @ U(cols)  [MFMA]
//    Phase B: 32-step chunk recurrence (256 serial lanes)
//    Phase C: Y(64x128) = Toep(64x64)@U + V(64x128)@S_in [MFMA] + D*u + GELU
// ---------------------------------------------------------------------------
__global__ __launch_bounds__(256) void ssm_chunk_kernel(
    const u16* __restrict__ XT, const float* __restrict__ P,
    const u16* __restrict__ Toep_bf, const float* __restrict__ D_skip,
    u16* __restrict__ YT)
{
    __shared__ u16 U[128 * 72];      // [ncol][j], pad 72
    __shared__ u16 S[128 * 136];     // [ncol][2n], pad 136
    __shared__ u16 EVT[13312];       // union: E[128*72]=9216 | Toep[64*72]=4608 + V[64*136]=8704
    u16* E  = EVT;
    u16* Tp = EVT;
    u16* V  = EVT + 4608;

    const int h    = blockIdx.x;
    const int b0   = blockIdx.y * 4;
    const int t    = threadIdx.x;
    const int lane = t & 63;
    const int wv   = t >> 6;
    const int lm   = lane & 15, lq = lane >> 4;

    const int pidx = (h << 6) + lane;
    const float wr  = P[pidx],          wi  = P[HN + pidx];
    const float c2r = P[2 * HN + pidx], c2i = P[3 * HN + pidx];

    // stage U: 128 rows x 64 bf16, 16B chunks (coalesced), padded LDS rows
    #pragma unroll
    for (int r = 0; r < 4; ++r) {
        int idx = t + r * 256;
        int row = idx >> 3, ch = idx & 7;
        const u16* gp = XT + (((size_t)(b0 + (row >> 5)) * H_DIM + h) << 11)
                           + ((row & 31) << 6) + (ch << 3);
        *(uint4*)&U[row * 72 + ch * 8] = *(const uint4*)gp;
    }

    // base power w^(16*wv) for this wave
    float bwr, bwi;
    {
        float g16r = wr, g16i = wi;
        csq(g16r, g16i); csq(g16r, g16i); csq(g16r, g16i); csq(g16r, g16i); // w^16
        if (wv == 0)      { bwr = 1.0f; bwi = 0.0f; }
        else if (wv == 1) { bwr = g16r; bwi = g16i; }
        else if (wv == 2) { bwr = g16r; bwi = g16i; csq(bwr, bwi); }
        else {
            float g32r = g16r, g32i = g16i; csq(g32r, g32i);
            bwr = g32r * g16r - g32i * g16i;
            bwi = g32r * g16i + g32i * g16r;
        }
    }

    // fill E: E[2n][j]=Re(w^(63-j)), E[2n+1][j]=Im(w^(63-j)); wave wv covers k=16wv..16wv+15
    {
        float pr = bwr, pi = bwi;
        #pragma unroll
        for (int jk = 0; jk < 16; ++jk) {
            int k = (wv << 4) + jk;
            int j = 63 - k;
            E[(2 * lane) * 72 + j]     = f2b(pr);
            E[(2 * lane + 1) * 72 + j] = f2b(pi);
            float nr = pr * wr - pi * wi, ni = pr * wi + pi * wr;
            pr = nr; pi = ni;
        }
    }
    __syncthreads();

    // Phase A: acc[m][ncol], m = state index (2n interleaved), ncol = (bloc,c)
    {
        const int wm = wv >> 1, wn = wv & 1;
        floatx4 acc[4][4] = {};
        #pragma unroll
        for (int ks = 0; ks < 2; ++ks) {
            bf16x8 af[4], bfv[4];
            #pragma unroll
            for (int i = 0; i < 4; ++i)
                af[i] = *(const bf16x8*)&E[(wm * 64 + i * 16 + lm) * 72 + ks * 32 + lq * 8];
            #pragma unroll
            for (int j = 0; j < 4; ++j)
                bfv[j] = *(const bf16x8*)&U[(wn * 64 + j * 16 + lm) * 72 + ks * 32 + lq * 8];
            #pragma unroll
            for (int i = 0; i < 4; ++i) {
                #pragma unroll
                for (int j = 0; j < 4; ++j)
                    acc[i][j] = __builtin_amdgcn_mfma_f32_16x16x32_bf16(af[i], bfv[j], acc[i][j], 0, 0, 0);
            }
        }
        #pragma unroll
        for (int i = 0; i < 4; ++i) {
            #pragma unroll
            for (int j = 0; j < 4; ++j) {
                int ncol = wn * 64 + j * 16 + lm;
                int m0   = wm * 64 + i * 16 + lq * 4;
                u16 pk[4];
                #pragma unroll
                for (int r = 0; r < 4; ++r) pk[r] = f2b(acc[i][j][r]);
                *(uint2*)&S[ncol * 136 + m0] = *(uint2*)pk;
            }
        }
    }
    __syncthreads();   // E reads + S_local writes complete

    // fill V (overwrites E region, disjoint from Toep) + stage Toep + chunk scan
    {
        // V: wave wv covers k = 16wv+1 .. 16wv+16; V[t=k-1][2n]=Re(Ct2 w^k), [2n+1]=-Im
        float pr = bwr, pi = bwi;
        {   // advance to k = 16wv+1
            float nr = pr * wr - pi * wi, ni = pr * wi + pi * wr;
            pr = nr; pi = ni;
        }
        #pragma unroll
        for (int jk = 1; jk <= 16; ++jk) {
            int tr = (wv << 4) + jk - 1;
            float qr = c2r * pr - c2i * pi;
            float qi = c2r * pi + c2i * pr;
            V[tr * 136 + 2 * lane]     = f2b(qr);
            V[tr * 136 + 2 * lane + 1] = f2b(-qi);
            float nr = pr * wr - pi * wi, ni = pr * wi + pi * wr;
            pr = nr; pi = ni;
        }
        // stage Toeplitz 64x64 -> [64][72]
        #pragma unroll
        for (int r = 0; r < 2; ++r) {
            int idx = t + r * 256;
            int row = idx >> 3, ch = idx & 7;
            *(uint4*)&Tp[row * 72 + ch * 8] =
                *(const uint4*)&Toep_bf[((size_t)h << 12) + (row << 6) + (ch << 3)];
        }
        // chunk scan: thread = chain (bloc = wv, n = lane); in-place S_local -> S_in
        float wTr = wr, wTi = wi;
        csq(wTr, wTi); csq(wTr, wTi); csq(wTr, wTi);
        csq(wTr, wTi); csq(wTr, wTi); csq(wTr, wTi);   // w^64
        float Sr = 0.0f, Si = 0.0f;
        const int n2 = lane * 2;
        for (int c = 0; c < 32; ++c) {
            int base = (wv * 32 + c) * 136 + n2;
            unsigned lv = *(unsigned*)&S[base];
            float lr, li;
            unpack2(lv, lr, li);
            *(unsigned*)&S[base] = pack2(Sr, Si);
            float nSr = wTr * Sr - wTi * Si + lr;
            Si = wTr * Si + wTi * Sr + li;
            Sr = nSr;
        }
    }
    __syncthreads();

    // Phase C: Y[t][ncol] = Toep@U + V@S_in; epilogue D*u + GELU -> YT (b,h,l)
    {
        const float Dh = D_skip[h];
        floatx4 acc[4][2] = {};
        #pragma unroll
        for (int ks = 0; ks < 6; ++ks) {
            bf16x8 af[4], bfv[2];
            if (ks < 2) {
                #pragma unroll
                for (int i = 0; i < 4; ++i)
                    af[i] = *(const bf16x8*)&Tp[(i * 16 + lm) * 72 + ks * 32 + lq * 8];
                #pragma unroll
                for (int j = 0; j < 2; ++j)
                    bfv[j] = *(const bf16x8*)&U[(wv * 32 + j * 16 + lm) * 72 + ks * 32 + lq * 8];
            } else {
                #pragma unroll
                for (int i = 0; i < 4; ++i)
                    af[i] = *(const bf16x8*)&V[(i * 16 + lm) * 136 + (ks - 2) * 32 + lq * 8];
                #pragma unroll
                for (int j = 0; j < 2; ++j)
                    bfv[j] = *(const bf16x8*)&S[(wv * 32 + j * 16 + lm) * 136 + (ks - 2) * 32 + lq * 8];
            }
            #pragma unroll
            for (int i = 0; i < 4; ++i) {
                #pragma unroll
                for (int j = 0; j < 2; ++j)
                    acc[i][j] = __builtin_amdgcn_mfma_f32_16x16x32_bf16(af[i], bfv[j], acc[i][j], 0, 0, 0);
            }
        }
        #pragma unroll
        for (int j = 0; j < 2; ++j) {
            int ncol = wv * 32 + j * 16 + lm;
            int bloc = ncol >> 5, c = ncol & 31;
            size_t gbase = (((size_t)(b0 + bloc) * H_DIM + h) << 11) + (c << 6);
            #pragma unroll
            for (int i = 0; i < 4; ++i) {
                int t0 = i * 16 + lq * 4;
                u16 upk[4];
                *(uint2*)upk = *(const uint2*)&U[ncol * 72 + t0];
                u16 opk[4];
                #pragma unroll
                for (int r = 0; r < 4; ++r) {
                    float uvv = b2f(upk[r]);
                    float yv = gelu_tanh_(fmaf(Dh, uvv, acc[i][j][r]));
                    opk[r] = f2b(yv);
                }
                *(uint2*)&YT[gbase + t0] = *(uint2*)opk;
            }
        }
    }
}

// ---------------------------------------------------------------------------
// 4) Transpose YT (B,H,L) bf16 -> Y (B,L,H) bf16
// ---------------------------------------------------------------------------
__global__ __launch_bounds__(256) void ytrans_kernel(
    const u16* __restrict__ YT, u16* __restrict__ Y)
{
    __shared__ u16 tile[32][33];
    int b  = blockIdx.z;
    int l0 = blockIdx.x * 32;
    int h0 = blockIdx.y * 32;
    int tx = threadIdx.x & 31;
    int ty = threadIdx.x >> 5;
    #pragma unroll
    for (int r = 0; r < 4; ++r)
        tile[ty + r * 8][tx] = YT[((size_t)b * H_DIM + h0 + ty + r * 8) * L_DIM + l0 + tx];
    __syncthreads();
    #pragma unroll
    for (int r = 0; r < 4; ++r)
        Y[((size_t)b * L_DIM + l0 + ty + r * 8) * H_DIM + h0 + tx] = tile[tx][ty + r * 8];
}

// ---------------------------------------------------------------------------
// stage a 128x32 bf16 tile (row-major, ld=512) into LDS via global_load_lds
// ---------------------------------------------------------------------------
__device__ __forceinline__ void stage_tile_128x32(
    const u16* __restrict__ g, u16* lds, int row0, int k0)
{
    const int t = threadIdx.x;
    #pragma unroll
    for (int r = 0; r < 2; ++r) {
        int row = (t >> 2) + r * 64;
        int col = (t & 3) * 8;
        const u16* gp = g + (size_t)(row0 + row) * 512 + k0 + col;
        __builtin_amdgcn_global_load_lds(
            (const __attribute__((address_space(1))) unsigned int*)gp,
            (__attribute__((address_space(3))) unsigned int*)(lds + (size_t)t * 8 + (size_t)r * 2048),
            16, 0, 0);
    }
}

// ---------------------------------------------------------------------------
// 5) GEMM1 + GLU + residual (dual-B). Double-buffered 2-phase pipeline,
//    expressed with plain __syncthreads (its vmcnt(0)+lgkmcnt(0)+barrier drain
//    lands AFTER the MFMA cluster -> prefetch latency hides under compute).
//    No inline-asm fences (they poisoned codegen in the previous attempt).
// ---------------------------------------------------------------------------
__global__ __launch_bounds__(256) void gemm1_glu_kernel(
    const u16* __restrict__ A, const u16* __restrict__ Wo,
    const float* __restrict__ bo, const float* __restrict__ x,
    u16* __restrict__ out)
{
    __shared__ u16 As[2][128 * 32];
    __shared__ u16 Ba[2][128 * 32];
    __shared__ u16 Bg[2][128 * 32];
    const int t    = threadIdx.x;
    const int lane = t & 63;
    const int wv   = t >> 6;
    const int wm   = wv >> 1, wn = wv & 1;
    const int lm   = lane & 15, lq = lane >> 4;
    const int m0   = blockIdx.x * 128, n0 = blockIdx.y * 128;
    floatx4 accA[4][4] = {};
    floatx4 accG[4][4] = {};

    // prologue: stage tile 0 into buffer 0
    stage_tile_128x32(A, As[0], m0, 0);
    stage_tile_128x32(Wo, Ba[0], n0, 0);
    stage_tile_128x32(Wo, Bg[0], 512 + n0, 0);
    __syncthreads();

    int cur = 0;
    for (int k0 = 32; k0 < 512; k0 += 32) {
        const int nx = cur ^ 1;
        // prefetch next K-tile; loads stay in flight during the MFMA cluster
        stage_tile_128x32(A, As[nx], m0, k0);
        stage_tile_128x32(Wo, Ba[nx], n0, k0);
        stage_tile_128x32(Wo, Bg[nx], 512 + n0, k0);

        bf16x8 af[4], ba[4], bg[4];
        #pragma unroll
        for (int i = 0; i < 4; ++i)
            af[i] = *(const bf16x8*)&As[cur][(wm * 64 + i * 16 + lm) * 32 + lq * 8];
        #pragma unroll
        for (int j = 0; j < 4; ++j) {
            ba[j] = *(const bf16x8*)&Ba[cur][(wn * 64 + j * 16 + lm) * 32 + lq * 8];
            bg[j] = *(const bf16x8*)&Bg[cur][(wn * 64 + j * 16 + lm) * 32 + lq * 8];
        }
        #pragma unroll
        for (int i = 0; i < 4; ++i) {
            #pragma unroll
            for (int j = 0; j < 4; ++j) {
                accA[i][j] = __builtin_amdgcn_mfma_f32_16x16x32_bf16(af[i], ba[j], accA[i][j], 0, 0, 0);
                accG[i][j] = __builtin_amdgcn_mfma_f32_16x16x32_bf16(af[i], bg[j], accG[i][j], 0, 0, 0);
            }
        }
        __syncthreads();   // drains prefetch (overlapped with MFMA) + syncs buffers
        cur = nx;
    }
    // final K-tile (no prefetch)
    {
        bf16x8 af[4], ba[4], bg[4];
        #pragma unroll
        for (int i = 0; i < 4; ++i)
            af[i] = *(const bf16x8*)&As[cur][(wm * 64 + i * 16 + lm) * 32 + lq * 8];
        #pragma unroll
        for (int j = 0; j < 4; ++j) {
            ba[j] = *(const bf16x8*)&Ba[cur][(wn * 64 + j * 16 + lm) * 32 + lq * 8];
            bg[j] = *(const bf16x8*)&Bg[cur][(wn * 64 + j * 16 + lm) * 32 + lq * 8];
        }
        #pragma unroll
        for (int i = 0; i < 4; ++i) {
            #pragma unroll
            for (int j = 0; j < 4; ++j) {
                accA[i][j] = __builtin_amdgcn_mfma_f32_16x16x32_bf16(af[i], ba[j], accA[i][j], 0, 0, 0);
                accG[i][j] = __builtin_amdgcn_mfma_f32_16x16x32_bf16(af[i], bg[j], accG[i][j], 0, 0, 0);
            }
        }
    }
    #pragma unroll
    for (int j = 0; j < 4; ++j) {
        int n = n0 + wn * 64 + j * 16 + lm;
        float bav = bo[n], bgv = bo[512 + n];
        #pragma unroll
        for (int i = 0; i < 4; ++i) {
            #pragma unroll
            for (int r = 0; r < 4; ++r) {
                int m = m0 + wm * 64 + i * 16 + lq * 4 + r;
                float av = accA[i][j][r] + bav;
                float gv = accG[i][j][r] + bgv;
                float xv = x[(size_t)m * 512 + n];
                out[(size_t)m * 512 + n] = f2b(fmaf(av, sigmoidf_(gv), xv));
            }
        }
    }
}

// ---------------------------------------------------------------------------
// 6/7) MFMA GEMM: C_bf16 = act(A[M,512]·Bw[512,512]^T + bias). EPI: 1=relu
//      Same double-buffered 2-phase structure (plain __syncthreads).
// ---------------------------------------------------------------------------
template<int EPI>
__global__ __launch_bounds__(256) void gemm_bt_bf_kernel(
    const u16* __restrict__ A, const u16* __restrict__ Bw,
    const float* __restrict__ bias, u16* __restrict__ C)
{
    __shared__ u16 As[2][128 * 32];
    __shared__ u16 Bs[2][128 * 32];
    const int t    = threadIdx.x;
    const int lane = t & 63;
    const int wv   = t >> 6;
    const int wm   = wv >> 1, wn = wv & 1;
    const int lm   = lane & 15, lq = lane >> 4;
    const int m0   = blockIdx.x * 128, n0 = blockIdx.y * 128;
    floatx4 acc[4][4] = {};

    stage_tile_128x32(A, As[0], m0, 0);
    stage_tile_128x32(Bw, Bs[0], n0, 0);
    __syncthreads();

    int cur = 0;
    for (int k0 = 32; k0 < 512; k0 += 32) {
        const int nx = cur ^ 1;
        stage_tile_128x32(A, As[nx], m0, k0);
        stage_tile_128x32(Bw, Bs[nx], n0, k0);

        bf16x8 af[4], bfr[4];
        #pragma unroll
        for (int i = 0; i < 4; ++i)
            af[i] = *(const bf16x8*)&As[cur][(wm * 64 + i * 16 + lm) * 32 + lq * 8];
        #pragma unroll
        for (int j = 0; j < 4; ++j)
            bfr[j] = *(const bf16x8*)&Bs[cur][(wn * 64 + j * 16 + lm) * 32 + lq * 8];
        #pragma unroll
        for (int i = 0; i < 4; ++i) {
            #pragma unroll
            for (int j = 0; j < 4; ++j)
                acc[i][j] = __builtin_amdgcn_mfma_f32_16x16x32_bf16(af[i], bfr[j], acc[i][j], 0, 0, 0);
        }
        __syncthreads();
        cur = nx;
    }
    {
        bf16x8 af[4], bfr[4];
        #pragma unroll
        for (int i = 0; i < 4; ++i)
            af[i] = *(const bf16x8*)&As[cur][(wm * 64 + i * 16 + lm) * 32 + lq * 8];
        #pragma unroll
        for (int j = 0; j < 4; ++j)
            bfr[j] = *(const bf16x8*)&Bs[cur][(wn * 64 + j * 16 + lm) * 32 + lq * 8];
        #pragma unroll
        for (int i = 0; i < 4; ++i) {
            #pragma unroll
            for (int j = 0; j < 4; ++j)
                acc[i][j] = __builtin_amdgcn_mfma_f32_16x16x32_bf16(af[i], bfr[j], acc[i][j], 0, 0, 0);
        }
    }
    #pragma unroll
    for (int j = 0; j < 4; ++j) {
        int n = n0 + wn * 64 + j * 16 + lm;
        float bv = bias[n];
        #pragma unroll
        for (int i = 0; i < 4; ++i) {
            #pragma unroll
            for (int r = 0; r < 4; ++r) {
                int m = m0 + wm * 64 + i * 16 + lq * 4 + r;
                float v = acc[i][j][r] + bv;
                if (EPI == 1) v = fmaxf(v, 0.0f);
                C[(size_t)m * 512 + n] = f2b(v);
            }
        }
    }
}

// ---------------------------------------------------------------------------
// 8) LayerNorm over H=512; bf16 in, optional bf16 residual; out bf16 or fp32
// ---------------------------------------------------------------------------
template<bool HASRES, bool F32OUT>
__global__ __launch_bounds__(256) void ln_bf_kernel(
    const u16* __restrict__ in, const u16* __restrict__ res,
    const float* __restrict__ gamma, const float* __restrict__ beta,
    u16* __restrict__ outb, float* __restrict__ outf)
{
    int w    = threadIdx.x >> 6;
    int lane = threadIdx.x & 63;
    size_t row  = (size_t)blockIdx.x * 4 + w;
    size_t base = row * 512 + lane * 8;
    uint4 raw = *(const uint4*)(in + base);
    float v[8];
    unpack2(raw.x, v[0], v[1]); unpack2(raw.y, v[2], v[3]);
    unpack2(raw.z, v[4], v[5]); unpack2(raw.w, v[6], v[7]);
    if (HASRES) {
        uint4 rr = *(const uint4*)(res + base);
        float rv[8];
        unpack2(rr.x, rv[0], rv[1]); unpack2(rr.y, rv[2], rv[3]);
        unpack2(rr.z, rv[4], rv[5]); unpack2(rr.w, rv[6], rv[7]);
        #pragma unroll
        for (int i = 0; i < 8; ++i) v[i] += rv[i];
    }
    float s = 0.0f, sq = 0.0f;
    #pragma unroll
    for (int i = 0; i < 8; ++i) { s += v[i]; sq = fmaf(v[i], v[i], sq); }
    #pragma unroll
    for (int m = 32; m > 0; m >>= 1) {
        s  += __shfl_xor(s, m, 64);
        sq += __shfl_xor(sq, m, 64);
    }
    float mu  = s * (1.0f / 512.0f);
    float var = sq * (1.0f / 512.0f) - mu * mu;
    float rs  = rsqrtf(var + 1e-5f);
    float g[8], bt[8];
    *(float4*)&g[0]  = *(const float4*)(gamma + lane * 8);
    *(float4*)&g[4]  = *(const float4*)(gamma + lane * 8 + 4);
    *(float4*)&bt[0] = *(const float4*)(beta + lane * 8);
    *(float4*)&bt[4] = *(const float4*)(beta + lane * 8 + 4);
    float o[8];
    #pragma unroll
    for (int i = 0; i < 8; ++i)
        o[i] = fmaf((v[i] - mu) * rs, g[i], bt[i]);
    if (F32OUT) {
        *(float4*)(outf + base)     = *(float4*)&o[0];
        *(float4*)(outf + base + 4) = *(float4*)&o[4];
    } else {
        uint4 p;
        p.x = pack2(o[0], o[1]); p.y = pack2(o[2], o[3]);
        p.z = pack2(o[4], o[5]); p.w = pack2(o[6], o[7]);
        *(uint4*)(outb + base) = p;
    }
}

// ---------------------------------------------------------------------------
extern "C" void kernel_launch(void* const* d_in, const int* in_sizes, int n_in,
                              void* d_out, int out_size, void* d_ws, size_t ws_size,
                              hipStream_t stream)
{
    (void)in_sizes; (void)n_in; (void)out_size; (void)ws_size;
    const float* x      = (const float*)d_in[0];
    const float* log_dt = (const float*)d_in[1];
    const float* A_re   = (const float*)d_in[2];
    const float* A_im   = (const float*)d_in[3];
    const float* C_re   = (const float*)d_in[4];
    const float* C_im   = (const float*)d_in[5];
    const float* D_skip = (const float*)d_in[6];
    const float* W_out  = (const float*)d_in[7];
    const float* b_out  = (const float*)d_in[8];
    const float* g1     = (const float*)d_in[9];
    const float* beta1  = (const float*)d_in[10];
    const float* g2     = (const float*)d_in[11];
    const float* beta2  = (const float*)d_in[12];
    const float* W1     = (const float*)d_in[13];
    const float* bc1    = (const float*)d_in[14];
    const float* W2     = (const float*)d_in[15];
    const float* bc2    = (const float*)d_in[16];
    float* out = (float*)d_out;

    // workspace: P 512K | Ktab 128K | Toep_bf 4M | weights 2M | r1/r2/r3 bf16 BLH
    char*  wsb    = (char*)d_ws;
    float* P      = (float*)wsb;
    float* Ktab   = (float*)(wsb + 4 * HN * 4);
    u16*   Toep   = (u16*)(wsb + 4 * HN * 4 + 512 * 64 * 4);
    u16*   Wobf   = Toep + 512 * 4096;
    u16*   W1bf   = Wobf + 1024 * 512;
    u16*   W2bf   = W1bf + 512 * 512;
    u16*   r1     = W2bf + 512 * 512;   // XT -> x1n_bf
    u16*   r2     = r1 + BLH;           // YT -> x1pre_bf -> y2_bf
    u16*   r3     = r2 + BLH;           // Y  -> h1_bf

    cast_kernel<<<512, 256, 0, stream>>>(W_out, Wobf);
    cast_kernel<<<256, 256, 0, stream>>>(W1, W1bf);
    cast_kernel<<<256, 256, 0, stream>>>(W2, W2bf);
    precompute_kernel<<<HN / 256, 256, 0, stream>>>(log_dt, A_re, A_im, C_re, C_im, P);
    ktab_kernel<<<128, 256, 0, stream>>>(P, Ktab);
    toepfill_kernel<<<8192, 256, 0, stream>>>(Ktab, Toep);
    xtrans_kernel<<<dim3(L_DIM / 32, H_DIM / 32, B_DIM), 256, 0, stream>>>(x, r1);
    ssm_chunk_kernel<<<dim3(H_DIM, 2), 256, 0, stream>>>(r1, P, Toep, D_skip, r2);
    ytrans_kernel<<<dim3(L_DIM / 32, H_DIM / 32, B_DIM), 256, 0, stream>>>(r2, r3);
    gemm1_glu_kernel<<<dim3(M_DIM / 128, 4), 256, 0, stream>>>(r3, Wobf, b_out, x, r2);
    ln_bf_kernel<false, false><<<M_DIM / 4, 256, 0, stream>>>(r2, nullptr, g1, beta1, r1, nullptr);
    gemm_bt_bf_kernel<1><<<dim3(M_DIM / 128, 4), 256, 0, stream>>>(r1, W1bf, bc1, r3);
    gemm_bt_bf_kernel<0><<<dim3(M_DIM / 128, 4), 256, 0, stream>>>(r3, W2bf, bc2, r2);
    ln_bf_kernel<true, true><<<M_DIM / 4, 256, 0, stream>>>(r2, r1, g2, beta2, nullptr, out);
}

// Round 3
// 250.557 us; speedup vs baseline: 1.1238x; 1.0131x over previous
//
#include <hip/hip_runtime.h>
#include <cstddef>
#include <cstdint>

#define B_DIM 8
#define L_DIM 2048
#define H_DIM 512
#define N_DIM 64
#define HN (H_DIM * N_DIM)          // 32768
#define BLH (B_DIM * L_DIM * H_DIM) // 8388608
#define M_DIM (B_DIM * L_DIM)       // 16384

typedef unsigned short u16;
typedef short bf16x8 __attribute__((ext_vector_type(8)));
typedef float floatx4 __attribute__((ext_vector_type(4)));

__device__ __forceinline__ float sigmoidf_(float v) {
    return 1.0f / (1.0f + __expf(-v));
}

// jax.nn.gelu default: approximate=True (tanh form)
__device__ __forceinline__ float gelu_tanh_(float x) {
    float x3 = x * x * x;
    float z = 0.7978845608028654f * fmaf(0.044715f, x3, x);
    float e = __expf(-2.0f * fabsf(z));
    float th = (1.0f - e) / (1.0f + e);
    th = copysignf(th, z);
    return 0.5f * x * (1.0f + th);
}

__device__ __forceinline__ u16 f2b(float f) {
    unsigned u = __float_as_uint(f);
    unsigned r = (u + 0x7fffu + ((u >> 16) & 1u)) >> 16;
    return (u16)r;
}
__device__ __forceinline__ float b2f(u16 u) {
    return __uint_as_float(((unsigned)u) << 16);
}
__device__ __forceinline__ void unpack2(unsigned u, float& a, float& b) {
    a = __uint_as_float(u << 16);
    b = __uint_as_float(u & 0xffff0000u);
}
__device__ __forceinline__ unsigned pack2(float a, float b) {
    return (unsigned)f2b(a) | ((unsigned)f2b(b) << 16);
}

// complex helpers
__device__ __forceinline__ void csq(float& r, float& i) {
    float nr = r * r - i * i;
    i = 2.0f * r * i;
    r = nr;
}

// ---------------------------------------------------------------------------
// 0) fp32 -> bf16 cast (weights)
// ---------------------------------------------------------------------------
__global__ __launch_bounds__(256) void cast_kernel(
    const float* __restrict__ src, u16* __restrict__ dst)
{
    int i = blockIdx.x * 256 + threadIdx.x;
    float4 v = *(const float4*)(src + (size_t)i * 4);
    uint2 p;
    p.x = pack2(v.x, v.y);
    p.y = pack2(v.z, v.w);
    *(uint2*)(dst + (size_t)i * 4) = p;
}

// ---------------------------------------------------------------------------
// 1) Per-(h,n) SSM params: w = exp(dt*A), Ct2 = 2*C*(exp(dt*A)-1)/A
// ---------------------------------------------------------------------------
__global__ __launch_bounds__(256) void precompute_kernel(
    const float* __restrict__ log_dt, const float* __restrict__ A_re,
    const float* __restrict__ A_im, const float* __restrict__ C_re,
    const float* __restrict__ C_im, float* __restrict__ P)
{
    int i = blockIdx.x * 256 + threadIdx.x;
    if (i >= HN) return;
    int h = i >> 6;
    float dt = expf(log_dt[h]);
    float Ar = A_re[i], Ai = A_im[i];
    float ar = dt * Ar, ai = dt * Ai;
    float e = expf(ar);
    float wr = e * cosf(ai);
    float wi = e * sinf(ai);
    float em1r = wr - 1.0f, em1i = wi;
    float inv = 1.0f / fmaf(Ar, Ar, Ai * Ai);
    float qr = fmaf(em1r, Ar, em1i * Ai) * inv;
    float qi = fmaf(em1i, Ar, -(em1r * Ai)) * inv;
    float Cr = C_re[i], Ci = C_im[i];
    float ctr = Cr * qr - Ci * qi;
    float cti = Cr * qi + Ci * qr;
    P[i]          = wr;
    P[HN + i]     = wi;
    P[2 * HN + i] = 2.0f * ctr;
    P[3 * HN + i] = 2.0f * cti;
}

// ---------------------------------------------------------------------------
// 1b) K table: K[h][tau] = sum_n Re(Ct2_n * w_n^tau), tau = 0..63
// ---------------------------------------------------------------------------
__global__ __launch_bounds__(256) void ktab_kernel(
    const float* __restrict__ P, float* __restrict__ Ktab)
{
    int wv = threadIdx.x >> 6, lane = threadIdx.x & 63;
    int h = blockIdx.x * 4 + wv;
    int pidx = (h << 6) + lane;
    float wr = P[pidx], wi = P[HN + pidx];
    float c2r = P[2 * HN + pidx], c2i = P[3 * HN + pidx];
    float pr = 1.0f, pi = 0.0f;
    for (int tau = 0; tau < 64; ++tau) {
        float term = c2r * pr - c2i * pi;
        #pragma unroll
        for (int m = 32; m > 0; m >>= 1) term += __shfl_xor(term, m, 64);
        if (lane == 0) Ktab[(h << 6) + tau] = term;
        float nr = pr * wr - pi * wi, ni = pr * wi + pi * wr;
        pr = nr; pi = ni;
    }
}

// ---------------------------------------------------------------------------
// 1c) Toeplitz fill: Toep_bf[h][t][j] = (j<=t) ? bf16(K[h][t-j]) : 0
// ---------------------------------------------------------------------------
__global__ __launch_bounds__(256) void toepfill_kernel(
    const float* __restrict__ Ktab, u16* __restrict__ Toep_bf)
{
    int idx = blockIdx.x * 256 + threadIdx.x;   // 512*4096
    int h = idx >> 12;
    int rem = idx & 4095;
    int tt = rem >> 6, j = rem & 63;
    u16 v = 0;
    if (j <= tt) v = f2b(Ktab[(h << 6) + (tt - j)]);
    Toep_bf[idx] = v;
}

// ---------------------------------------------------------------------------
// 2) Transpose x (B,L,H) fp32 -> XT (B,H,L) bf16
// ---------------------------------------------------------------------------
__global__ __launch_bounds__(256) void xtrans_kernel(
    const float* __restrict__ x, u16* __restrict__ XT)
{
    __shared__ float tile[32][33];
    int b  = blockIdx.z;
    int l0 = blockIdx.x * 32;
    int h0 = blockIdx.y * 32;
    int tx = threadIdx.x & 31;
    int ty = threadIdx.x >> 5;
    #pragma unroll
    for (int r = 0; r < 4; ++r)
        tile[ty + r * 8][tx] = x[((size_t)b * L_DIM + l0 + ty + r * 8) * H_DIM + h0 + tx];
    __syncthreads();
    #pragma unroll
    for (int r = 0; r < 4; ++r)
        XT[((size_t)b * H_DIM + h0 + ty + r * 8) * L_DIM + l0 + tx] = f2b(tile[tx][ty + r * 8]);
}

// ---------------------------------------------------------------------------
// 3) Chunked SSM via MFMA. One workgroup = (h, half of b). T=64, 32 chunks.
//    Phase A: S_local(128x128) = E(128x64) @ U(cols)  [MFMA]
//    Phase B: 32-step chunk recurrence (256 serial lanes)
//    Phase C: Y(64x128) = Toep(64x64)@U + V(64x128)@S_in [MFMA] + D*u + GELU
// ---------------------------------------------------------------------------
__global__ __launch_bounds__(256) void ssm_chunk_kernel(
    const u16* __restrict__ XT, const float* __restrict__ P,
    const u16* __restrict__ Toep_bf, const float* __restrict__ D_skip,
    u16* __restrict__ YT)
{
    __shared__ u16 U[128 * 72];      // [ncol][j], pad 72
    __shared__ u16 S[128 * 136];     // [ncol][2n], pad 136
    __shared__ u16 EVT[13312];       // union: E[128*72]=9216 | Toep[64*72]=4608 + V[64*136]=8704
    u16* E  = EVT;
    u16* Tp = EVT;
    u16* V  = EVT + 4608;

    const int h    = blockIdx.x;
    const int b0   = blockIdx.y * 4;
    const int t    = threadIdx.x;
    const int lane = t & 63;
    const int wv   = t >> 6;
    const int lm   = lane & 15, lq = lane >> 4;

    const int pidx = (h << 6) + lane;
    const float wr  = P[pidx],          wi  = P[HN + pidx];
    const float c2r = P[2 * HN + pidx], c2i = P[3 * HN + pidx];

    // stage U: 128 rows x 64 bf16, 16B chunks (coalesced), padded LDS rows
    #pragma unroll
    for (int r = 0; r < 4; ++r) {
        int idx = t + r * 256;
        int row = idx >> 3, ch = idx & 7;
        const u16* gp = XT + (((size_t)(b0 + (row >> 5)) * H_DIM + h) << 11)
                           + ((row & 31) << 6) + (ch << 3);
        *(uint4*)&U[row * 72 + ch * 8] = *(const uint4*)gp;
    }

    // base power w^(16*wv) for this wave
    float bwr, bwi;
    {
        float g16r = wr, g16i = wi;
        csq(g16r, g16i); csq(g16r, g16i); csq(g16r, g16i); csq(g16r, g16i); // w^16
        if (wv == 0)      { bwr = 1.0f; bwi = 0.0f; }
        else if (wv == 1) { bwr = g16r; bwi = g16i; }
        else if (wv == 2) { bwr = g16r; bwi = g16i; csq(bwr, bwi); }
        else {
            float g32r = g16r, g32i = g16i; csq(g32r, g32i);
            bwr = g32r * g16r - g32i * g16i;
            bwi = g32r * g16i + g32i * g16r;
        }
    }

    // fill E: E[2n][j]=Re(w^(63-j)), E[2n+1][j]=Im(w^(63-j)); wave wv covers k=16wv..16wv+15
    {
        float pr = bwr, pi = bwi;
        #pragma unroll
        for (int jk = 0; jk < 16; ++jk) {
            int k = (wv << 4) + jk;
            int j = 63 - k;
            E[(2 * lane) * 72 + j]     = f2b(pr);
            E[(2 * lane + 1) * 72 + j] = f2b(pi);
            float nr = pr * wr - pi * wi, ni = pr * wi + pi * wr;
            pr = nr; pi = ni;
        }
    }
    __syncthreads();

    // Phase A: acc[m][ncol], m = state index (2n interleaved), ncol = (bloc,c)
    {
        const int wm = wv >> 1, wn = wv & 1;
        floatx4 acc[4][4] = {};
        #pragma unroll
        for (int ks = 0; ks < 2; ++ks) {
            bf16x8 af[4], bfv[4];
            #pragma unroll
            for (int i = 0; i < 4; ++i)
                af[i] = *(const bf16x8*)&E[(wm * 64 + i * 16 + lm) * 72 + ks * 32 + lq * 8];
            #pragma unroll
            for (int j = 0; j < 4; ++j)
                bfv[j] = *(const bf16x8*)&U[(wn * 64 + j * 16 + lm) * 72 + ks * 32 + lq * 8];
            #pragma unroll
            for (int i = 0; i < 4; ++i) {
                #pragma unroll
                for (int j = 0; j < 4; ++j)
                    acc[i][j] = __builtin_amdgcn_mfma_f32_16x16x32_bf16(af[i], bfv[j], acc[i][j], 0, 0, 0);
            }
        }
        #pragma unroll
        for (int i = 0; i < 4; ++i) {
            #pragma unroll
            for (int j = 0; j < 4; ++j) {
                int ncol = wn * 64 + j * 16 + lm;
                int m0   = wm * 64 + i * 16 + lq * 4;
                u16 pk[4];
                #pragma unroll
                for (int r = 0; r < 4; ++r) pk[r] = f2b(acc[i][j][r]);
                *(uint2*)&S[ncol * 136 + m0] = *(uint2*)pk;
            }
        }
    }
    __syncthreads();   // E reads + S_local writes complete

    // fill V (overwrites E region, disjoint from Toep) + stage Toep + chunk scan
    {
        // V: wave wv covers k = 16wv+1 .. 16wv+16; V[t=k-1][2n]=Re(Ct2 w^k), [2n+1]=-Im
        float pr = bwr, pi = bwi;
        {   // advance to k = 16wv+1
            float nr = pr * wr - pi * wi, ni = pr * wi + pi * wr;
            pr = nr; pi = ni;
        }
        #pragma unroll
        for (int jk = 1; jk <= 16; ++jk) {
            int tr = (wv << 4) + jk - 1;
            float qr = c2r * pr - c2i * pi;
            float qi = c2r * pi + c2i * pr;
            V[tr * 136 + 2 * lane]     = f2b(qr);
            V[tr * 136 + 2 * lane + 1] = f2b(-qi);
            float nr = pr * wr - pi * wi, ni = pr * wi + pi * wr;
            pr = nr; pi = ni;
        }
        // stage Toeplitz 64x64 -> [64][72]
        #pragma unroll
        for (int r = 0; r < 2; ++r) {
            int idx = t + r * 256;
            int row = idx >> 3, ch = idx & 7;
            *(uint4*)&Tp[row * 72 + ch * 8] =
                *(const uint4*)&Toep_bf[((size_t)h << 12) + (row << 6) + (ch << 3)];
        }
        // chunk scan: thread = chain (bloc = wv, n = lane); in-place S_local -> S_in
        float wTr = wr, wTi = wi;
        csq(wTr, wTi); csq(wTr, wTi); csq(wTr, wTi);
        csq(wTr, wTi); csq(wTr, wTi); csq(wTr, wTi);   // w^64
        float Sr = 0.0f, Si = 0.0f;
        const int n2 = lane * 2;
        for (int c = 0; c < 32; ++c) {
            int base = (wv * 32 + c) * 136 + n2;
            unsigned lv = *(unsigned*)&S[base];
            float lr, li;
            unpack2(lv, lr, li);
            *(unsigned*)&S[base] = pack2(Sr, Si);
            float nSr = wTr * Sr - wTi * Si + lr;
            Si = wTr * Si + wTi * Sr + li;
            Sr = nSr;
        }
    }
    __syncthreads();

    // Phase C: Y[t][ncol] = Toep@U + V@S_in; epilogue D*u + GELU -> YT (b,h,l)
    {
        const float Dh = D_skip[h];
        floatx4 acc[4][2] = {};
        #pragma unroll
        for (int ks = 0; ks < 6; ++ks) {
            bf16x8 af[4], bfv[2];
            if (ks < 2) {
                #pragma unroll
                for (int i = 0; i < 4; ++i)
                    af[i] = *(const bf16x8*)&Tp[(i * 16 + lm) * 72 + ks * 32 + lq * 8];
                #pragma unroll
                for (int j = 0; j < 2; ++j)
                    bfv[j] = *(const bf16x8*)&U[(wv * 32 + j * 16 + lm) * 72 + ks * 32 + lq * 8];
            } else {
                #pragma unroll
                for (int i = 0; i < 4; ++i)
                    af[i] = *(const bf16x8*)&V[(i * 16 + lm) * 136 + (ks - 2) * 32 + lq * 8];
                #pragma unroll
                for (int j = 0; j < 2; ++j)
                    bfv[j] = *(const bf16x8*)&S[(wv * 32 + j * 16 + lm) * 136 + (ks - 2) * 32 + lq * 8];
            }
            #pragma unroll
            for (int i = 0; i < 4; ++i) {
                #pragma unroll
                for (int j = 0; j < 2; ++j)
                    acc[i][j] = __builtin_amdgcn_mfma_f32_16x16x32_bf16(af[i], bfv[j], acc[i][j], 0, 0, 0);
            }
        }
        #pragma unroll
        for (int j = 0; j < 2; ++j) {
            int ncol = wv * 32 + j * 16 + lm;
            int bloc = ncol >> 5, c = ncol & 31;
            size_t gbase = (((size_t)(b0 + bloc) * H_DIM + h) << 11) + (c << 6);
            #pragma unroll
            for (int i = 0; i < 4; ++i) {
                int t0 = i * 16 + lq * 4;
                u16 upk[4];
                *(uint2*)upk = *(const uint2*)&U[ncol * 72 + t0];
                u16 opk[4];
                #pragma unroll
                for (int r = 0; r < 4; ++r) {
                    float uvv = b2f(upk[r]);
                    float yv = gelu_tanh_(fmaf(Dh, uvv, acc[i][j][r]));
                    opk[r] = f2b(yv);
                }
                *(uint2*)&YT[gbase + t0] = *(uint2*)opk;
            }
        }
    }
}

// ---------------------------------------------------------------------------
// 4) Transpose YT (B,H,L) bf16 -> Y (B,L,H) bf16
// ---------------------------------------------------------------------------
__global__ __launch_bounds__(256) void ytrans_kernel(
    const u16* __restrict__ YT, u16* __restrict__ Y)
{
    __shared__ u16 tile[32][33];
    int b  = blockIdx.z;
    int l0 = blockIdx.x * 32;
    int h0 = blockIdx.y * 32;
    int tx = threadIdx.x & 31;
    int ty = threadIdx.x >> 5;
    #pragma unroll
    for (int r = 0; r < 4; ++r)
        tile[ty + r * 8][tx] = YT[((size_t)b * H_DIM + h0 + ty + r * 8) * L_DIM + l0 + tx];
    __syncthreads();
    #pragma unroll
    for (int r = 0; r < 4; ++r)
        Y[((size_t)b * L_DIM + l0 + ty + r * 8) * H_DIM + h0 + tx] = tile[tx][ty + r * 8];
}

// ---------------------------------------------------------------------------
// stage a 128x32 bf16 tile into LDS via global_load_lds, 512 threads.
// LDS dest is LINEAR (rule: global_load_lds can't scatter); the bank-conflict
// swizzle is applied by permuting the GLOBAL source 16B-chunk, chunk' =
// chunk ^ ((row>>1)&3). Readers XOR their column the same way (per-thread
// constant). Spreads 16-lane fragment reads over 8 bank-groups: 8-way -> 2-way.
// ---------------------------------------------------------------------------
__device__ __forceinline__ void stage_tile_512(
    const u16* __restrict__ g, u16* lds, int row0, int k0)
{
    const int t = threadIdx.x;           // 0..511, one 16B chunk each
    const int row  = t >> 2;             // 0..127
    const int csrc = (t & 3) ^ ((t >> 3) & 3);
    const u16* gp = g + (size_t)(row0 + row) * 512 + k0 + csrc * 8;
    __builtin_amdgcn_global_load_lds(
        (const __attribute__((address_space(1))) unsigned int*)gp,
        (__attribute__((address_space(3))) unsigned int*)(lds + (size_t)t * 8),
        16, 0, 0);
}

// ---------------------------------------------------------------------------
// 5) GEMM1 + GLU + residual (dual-B). 512 threads (8 waves, 2m x 4n) for
//    4 waves/SIMD at 2 blocks/CU (latency-bound fix). Double-buffered
//    2-phase pipeline with plain __syncthreads. Swizzled LDS reads.
// ---------------------------------------------------------------------------
__global__ __launch_bounds__(512) void gemm1_glu_kernel(
    const u16* __restrict__ A, const u16* __restrict__ Wo,
    const float* __restrict__ bo, const float* __restrict__ x,
    u16* __restrict__ out)
{
    __shared__ u16 As[2][128 * 32];
    __shared__ u16 Ba[2][128 * 32];
    __shared__ u16 Bg[2][128 * 32];
    const int t    = threadIdx.x;
    const int lane = t & 63;
    const int wv   = t >> 6;             // 0..7
    const int wm   = wv >> 2, wn = wv & 3;
    const int lm   = lane & 15, lq = lane >> 4;
    const int sw   = (lq ^ ((lm >> 1) & 3)) * 8;   // swizzled 16B-chunk column
    const int m0   = blockIdx.x * 128, n0 = blockIdx.y * 128;
    floatx4 accA[4][2] = {};
    floatx4 accG[4][2] = {};

    // prologue: stage tile 0 into buffer 0
    stage_tile_512(A, As[0], m0, 0);
    stage_tile_512(Wo, Ba[0], n0, 0);
    stage_tile_512(Wo, Bg[0], 512 + n0, 0);
    __syncthreads();

    int cur = 0;
    for (int k0 = 32; k0 < 512; k0 += 32) {
        const int nx = cur ^ 1;
        // prefetch next K-tile; loads stay in flight during the MFMA cluster
        stage_tile_512(A, As[nx], m0, k0);
        stage_tile_512(Wo, Ba[nx], n0, k0);
        stage_tile_512(Wo, Bg[nx], 512 + n0, k0);

        bf16x8 af[4], ba[2], bg[2];
        #pragma unroll
        for (int i = 0; i < 4; ++i)
            af[i] = *(const bf16x8*)&As[cur][(wm * 64 + i * 16 + lm) * 32 + sw];
        #pragma unroll
        for (int j = 0; j < 2; ++j) {
            ba[j] = *(const bf16x8*)&Ba[cur][(wn * 32 + j * 16 + lm) * 32 + sw];
            bg[j] = *(const bf16x8*)&Bg[cur][(wn * 32 + j * 16 + lm) * 32 + sw];
        }
        #pragma unroll
        for (int i = 0; i < 4; ++i) {
            #pragma unroll
            for (int j = 0; j < 2; ++j) {
                accA[i][j] = __builtin_amdgcn_mfma_f32_16x16x32_bf16(af[i], ba[j], accA[i][j], 0, 0, 0);
                accG[i][j] = __builtin_amdgcn_mfma_f32_16x16x32_bf16(af[i], bg[j], accG[i][j], 0, 0, 0);
            }
        }
        __syncthreads();   // drains prefetch (overlapped with MFMA) + syncs buffers
        cur = nx;
    }
    // final K-tile (no prefetch)
    {
        bf16x8 af[4], ba[2], bg[2];
        #pragma unroll
        for (int i = 0; i < 4; ++i)
            af[i] = *(const bf16x8*)&As[cur][(wm * 64 + i * 16 + lm) * 32 + sw];
        #pragma unroll
        for (int j = 0; j < 2; ++j) {
            ba[j] = *(const bf16x8*)&Ba[cur][(wn * 32 + j * 16 + lm) * 32 + sw];
            bg[j] = *(const bf16x8*)&Bg[cur][(wn * 32 + j * 16 + lm) * 32 + sw];
        }
        #pragma unroll
        for (int i = 0; i < 4; ++i) {
            #pragma unroll
            for (int j = 0; j < 2; ++j) {
                accA[i][j] = __builtin_amdgcn_mfma_f32_16x16x32_bf16(af[i], ba[j], accA[i][j], 0, 0, 0);
                accG[i][j] = __builtin_amdgcn_mfma_f32_16x16x32_bf16(af[i], bg[j], accG[i][j], 0, 0, 0);
            }
        }
    }
    #pragma unroll
    for (int j = 0; j < 2; ++j) {
        int n = n0 + wn * 32 + j * 16 + lm;
        float bav = bo[n], bgv = bo[512 + n];
        #pragma unroll
        for (int i = 0; i < 4; ++i) {
            #pragma unroll
            for (int r = 0; r < 4; ++r) {
                int m = m0 + wm * 64 + i * 16 + lq * 4 + r;
                float av = accA[i][j][r] + bav;
                float gv = accG[i][j][r] + bgv;
                float xv = x[(size_t)m * 512 + n];
                out[(size_t)m * 512 + n] = f2b(fmaf(av, sigmoidf_(gv), xv));
            }
        }
    }
}

// ---------------------------------------------------------------------------
// 6/7) MFMA GEMM: C_bf16 = act(A[M,512]·Bw[512,512]^T + bias). EPI: 1=relu
//      512 threads (8 waves, 2m x 4n), double-buffered, swizzled LDS reads.
// ---------------------------------------------------------------------------
template<int EPI>
__global__ __launch_bounds__(512) void gemm_bt_bf_kernel(
    const u16* __restrict__ A, const u16* __restrict__ Bw,
    const float* __restrict__ bias, u16* __restrict__ C)
{
    __shared__ u16 As[2][128 * 32];
    __shared__ u16 Bs[2][128 * 32];
    const int t    = threadIdx.x;
    const int lane = t & 63;
    const int wv   = t >> 6;
    const int wm   = wv >> 2, wn = wv & 3;
    const int lm   = lane & 15, lq = lane >> 4;
    const int sw   = (lq ^ ((lm >> 1) & 3)) * 8;
    const int m0   = blockIdx.x * 128, n0 = blockIdx.y * 128;
    floatx4 acc[4][2] = {};

    stage_tile_512(A, As[0], m0, 0);
    stage_tile_512(Bw, Bs[0], n0, 0);
    __syncthreads();

    int cur = 0;
    for (int k0 = 32; k0 < 512; k0 += 32) {
        const int nx = cur ^ 1;
        stage_tile_512(A, As[nx], m0, k0);
        stage_tile_512(Bw, Bs[nx], n0, k0);

        bf16x8 af[4], bfr[2];
        #pragma unroll
        for (int i = 0; i < 4; ++i)
            af[i] = *(const bf16x8*)&As[cur][(wm * 64 + i * 16 + lm) * 32 + sw];
        #pragma unroll
        for (int j = 0; j < 2; ++j)
            bfr[j] = *(const bf16x8*)&Bs[cur][(wn * 32 + j * 16 + lm) * 32 + sw];
        #pragma unroll
        for (int i = 0; i < 4; ++i) {
            #pragma unroll
            for (int j = 0; j < 2; ++j)
                acc[i][j] = __builtin_amdgcn_mfma_f32_16x16x32_bf16(af[i], bfr[j], acc[i][j], 0, 0, 0);
        }
        __syncthreads();
        cur = nx;
    }
    {
        bf16x8 af[4], bfr[2];
        #pragma unroll
        for (int i = 0; i < 4; ++i)
            af[i] = *(const bf16x8*)&As[cur][(wm * 64 + i * 16 + lm) * 32 + sw];
        #pragma unroll
        for (int j = 0; j < 2; ++j)
            bfr[j] = *(const bf16x8*)&Bs[cur][(wn * 32 + j * 16 + lm) * 32 + sw];
        #pragma unroll
        for (int i = 0; i < 4; ++i) {
            #pragma unroll
            for (int j = 0; j < 2; ++j)
                acc[i][j] = __builtin_amdgcn_mfma_f32_16x16x32_bf16(af[i], bfr[j], acc[i][j], 0, 0, 0);
        }
    }
    #pragma unroll
    for (int j = 0; j < 2; ++j) {
        int n = n0 + wn * 32 + j * 16 + lm;
        float bv = bias[n];
        #pragma unroll
        for (int i = 0; i < 4; ++i) {
            #pragma unroll
            for (int r = 0; r < 4; ++r) {
                int m = m0 + wm * 64 + i * 16 + lq * 4 + r;
                float v = acc[i][j][r] + bv;
                if (EPI == 1) v = fmaxf(v, 0.0f);
                C[(size_t)m * 512 + n] = f2b(v);
            }
        }
    }
}

// ---------------------------------------------------------------------------
// 8) LayerNorm over H=512; bf16 in, optional bf16 residual; out bf16 or fp32
// ---------------------------------------------------------------------------
template<bool HASRES, bool F32OUT>
__global__ __launch_bounds__(256) void ln_bf_kernel(
    const u16* __restrict__ in, const u16* __restrict__ res,
    const float* __restrict__ gamma, const float* __restrict__ beta,
    u16* __restrict__ outb, float* __restrict__ outf)
{
    int w    = threadIdx.x >> 6;
    int lane = threadIdx.x & 63;
    size_t row  = (size_t)blockIdx.x * 4 + w;
    size_t base = row * 512 + lane * 8;
    uint4 raw = *(const uint4*)(in + base);
    float v[8];
    unpack2(raw.x, v[0], v[1]); unpack2(raw.y, v[2], v[3]);
    unpack2(raw.z, v[4], v[5]); unpack2(raw.w, v[6], v[7]);
    if (HASRES) {
        uint4 rr = *(const uint4*)(res + base);
        float rv[8];
        unpack2(rr.x, rv[0], rv[1]); unpack2(rr.y, rv[2], rv[3]);
        unpack2(rr.z, rv[4], rv[5]); unpack2(rr.w, rv[6], rv[7]);
        #pragma unroll
        for (int i = 0; i < 8; ++i) v[i] += rv[i];
    }
    float s = 0.0f, sq = 0.0f;
    #pragma unroll
    for (int i = 0; i < 8; ++i) { s += v[i]; sq = fmaf(v[i], v[i], sq); }
    #pragma unroll
    for (int m = 32; m > 0; m >>= 1) {
        s  += __shfl_xor(s, m, 64);
        sq += __shfl_xor(sq, m, 64);
    }
    float mu  = s * (1.0f / 512.0f);
    float var = sq * (1.0f / 512.0f) - mu * mu;
    float rs  = rsqrtf(var + 1e-5f);
    float g[8], bt[8];
    *(float4*)&g[0]  = *(const float4*)(gamma + lane * 8);
    *(float4*)&g[4]  = *(const float4*)(gamma + lane * 8 + 4);
    *(float4*)&bt[0] = *(const float4*)(beta + lane * 8);
    *(float4*)&bt[4] = *(const float4*)(beta + lane * 8 + 4);
    float o[8];
    #pragma unroll
    for (int i = 0; i < 8; ++i)
        o[i] = fmaf((v[i] - mu) * rs, g[i], bt[i]);
    if (F32OUT) {
        *(float4*)(outf + base)     = *(float4*)&o[0];
        *(float4*)(outf + base + 4) = *(float4*)&o[4];
    } else {
        uint4 p;
        p.x = pack2(o[0], o[1]); p.y = pack2(o[2], o[3]);
        p.z = pack2(o[4], o[5]); p.w = pack2(o[6], o[7]);
        *(uint4*)(outb + base) = p;
    }
}

// ---------------------------------------------------------------------------
extern "C" void kernel_launch(void* const* d_in, const int* in_sizes, int n_in,
                              void* d_out, int out_size, void* d_ws, size_t ws_size,
                              hipStream_t stream)
{
    (void)in_sizes; (void)n_in; (void)out_size; (void)ws_size;
    const float* x      = (const float*)d_in[0];
    const float* log_dt = (const float*)d_in[1];
    const float* A_re   = (const float*)d_in[2];
    const float* A_im   = (const float*)d_in[3];
    const float* C_re   = (const float*)d_in[4];
    const float* C_im   = (const float*)d_in[5];
    const float* D_skip = (const float*)d_in[6];
    const float* W_out  = (const float*)d_in[7];
    const float* b_out  = (const float*)d_in[8];
    const float* g1     = (const float*)d_in[9];
    const float* beta1  = (const float*)d_in[10];
    const float* g2     = (const float*)d_in[11];
    const float* beta2  = (const float*)d_in[12];
    const float* W1     = (const float*)d_in[13];
    const float* bc1    = (const float*)d_in[14];
    const float* W2     = (const float*)d_in[15];
    const float* bc2    = (const float*)d_in[16];
    float* out = (float*)d_out;

    // workspace: P 512K | Ktab 128K | Toep_bf 4M | weights 2M | r1/r2/r3 bf16 BLH
    char*  wsb    = (char*)d_ws;
    float* P      = (float*)wsb;
    float* Ktab   = (float*)(wsb + 4 * HN * 4);
    u16*   Toep   = (u16*)(wsb + 4 * HN * 4 + 512 * 64 * 4);
    u16*   Wobf   = Toep + 512 * 4096;
    u16*   W1bf   = Wobf + 1024 * 512;
    u16*   W2bf   = W1bf + 512 * 512;
    u16*   r1     = W2bf + 512 * 512;   // XT -> x1n_bf
    u16*   r2     = r1 + BLH;           // YT -> x1pre_bf -> y2_bf
    u16*   r3     = r2 + BLH;           // Y  -> h1_bf

    cast_kernel<<<512, 256, 0, stream>>>(W_out, Wobf);
    cast_kernel<<<256, 256, 0, stream>>>(W1, W1bf);
    cast_kernel<<<256, 256, 0, stream>>>(W2, W2bf);
    precompute_kernel<<<HN / 256, 256, 0, stream>>>(log_dt, A_re, A_im, C_re, C_im, P);
    ktab_kernel<<<128, 256, 0, stream>>>(P, Ktab);
    toepfill_kernel<<<8192, 256, 0, stream>>>(Ktab, Toep);
    xtrans_kernel<<<dim3(L_DIM / 32, H_DIM / 32, B_DIM), 256, 0, stream>>>(x, r1);
    ssm_chunk_kernel<<<dim3(H_DIM, 2), 256, 0, stream>>>(r1, P, Toep, D_skip, r2);
    ytrans_kernel<<<dim3(L_DIM / 32, H_DIM / 32, B_DIM), 256, 0, stream>>>(r2, r3);
    gemm1_glu_kernel<<<dim3(M_DIM / 128, 4), 512, 0, stream>>>(r3, Wobf, b_out, x, r2);
    ln_bf_kernel<false, false><<<M_DIM / 4, 256, 0, stream>>>(r2, nullptr, g1, beta1, r1, nullptr);
    gemm_bt_bf_kernel<1><<<dim3(M_DIM / 128, 4), 512, 0, stream>>>(r1, W1bf, bc1, r3);
    gemm_bt_bf_kernel<0><<<dim3(M_DIM / 128, 4), 512, 0, stream>>>(r3, W2bf, bc2, r2);
    ln_bf_kernel<true, true><<<M_DIM / 4, 256, 0, stream>>>(r2, r1, g2, beta2, nullptr, out);
}

// Round 4
// 245.072 us; speedup vs baseline: 1.1490x; 1.0224x over previous
//
#include <hip/hip_runtime.h>
#include <cstddef>
#include <cstdint>

#define B_DIM 8
#define L_DIM 2048
#define H_DIM 512
#define N_DIM 64
#define HN (H_DIM * N_DIM)          // 32768
#define BLH (B_DIM * L_DIM * H_DIM) // 8388608
#define M_DIM (B_DIM * L_DIM)       // 16384

typedef unsigned short u16;
typedef short bf16x8 __attribute__((ext_vector_type(8)));
typedef float floatx4 __attribute__((ext_vector_type(4)));

__device__ __forceinline__ float sigmoidf_(float v) {
    return 1.0f / (1.0f + __expf(-v));
}

// jax.nn.gelu default: approximate=True (tanh form)
__device__ __forceinline__ float gelu_tanh_(float x) {
    float x3 = x * x * x;
    float z = 0.7978845608028654f * fmaf(0.044715f, x3, x);
    float e = __expf(-2.0f * fabsf(z));
    float th = (1.0f - e) / (1.0f + e);
    th = copysignf(th, z);
    return 0.5f * x * (1.0f + th);
}

__device__ __forceinline__ u16 f2b(float f) {
    unsigned u = __float_as_uint(f);
    unsigned r = (u + 0x7fffu + ((u >> 16) & 1u)) >> 16;
    return (u16)r;
}
__device__ __forceinline__ float b2f(u16 u) {
    return __uint_as_float(((unsigned)u) << 16);
}
__device__ __forceinline__ void unpack2(unsigned u, float& a, float& b) {
    a = __uint_as_float(u << 16);
    b = __uint_as_float(u & 0xffff0000u);
}
__device__ __forceinline__ unsigned pack2(float a, float b) {
    return (unsigned)f2b(a) | ((unsigned)f2b(b) << 16);
}

// complex helpers
__device__ __forceinline__ void csq(float& r, float& i) {
    float nr = r * r - i * i;
    i = 2.0f * r * i;
    r = nr;
}

// ---------------------------------------------------------------------------
// 0) fp32 -> bf16 cast for all three weight matrices in one launch.
//    blocks: [0,512) Wo (1024x512), [512,768) W1, [768,1024) W2
// ---------------------------------------------------------------------------
__global__ __launch_bounds__(256) void cast3_kernel(
    const float* __restrict__ s0, const float* __restrict__ s1,
    const float* __restrict__ s2, u16* __restrict__ d0,
    u16* __restrict__ d1, u16* __restrict__ d2)
{
    int bid = blockIdx.x;
    const float* src; u16* dst; int off;
    if (bid < 512)      { src = s0; dst = d0; off = bid; }
    else if (bid < 768) { src = s1; dst = d1; off = bid - 512; }
    else                { src = s2; dst = d2; off = bid - 768; }
    int i = off * 256 + threadIdx.x;
    float4 v = *(const float4*)(src + (size_t)i * 4);
    uint2 p;
    p.x = pack2(v.x, v.y);
    p.y = pack2(v.z, v.w);
    *(uint2*)(dst + (size_t)i * 4) = p;
}

// ---------------------------------------------------------------------------
// 1) Fused SSM parameter setup: per-(h,n) P = {w, Ct2}, K table (in LDS),
//    and Toeplitz fill — one launch, Ktab never touches HBM.
//    Block = 4 heads (wave wv <-> head), lane = n.
// ---------------------------------------------------------------------------
__global__ __launch_bounds__(256) void params_kernel(
    const float* __restrict__ log_dt, const float* __restrict__ A_re,
    const float* __restrict__ A_im, const float* __restrict__ C_re,
    const float* __restrict__ C_im, float* __restrict__ P,
    u16* __restrict__ Toep_bf)
{
    __shared__ float ktab_s[4][64];
    const int t = threadIdx.x;
    const int wv = t >> 6, lane = t & 63;
    const int i = blockIdx.x * 256 + t;       // (h,n) flat
    const int h = i >> 6;

    // --- precompute: w = exp(dt*A), Ct2 = 2*C*(exp(dt*A)-1)/A
    float dt = expf(log_dt[h]);
    float Ar = A_re[i], Ai = A_im[i];
    float ar = dt * Ar, ai = dt * Ai;
    float e = expf(ar);
    float wr = e * cosf(ai);
    float wi = e * sinf(ai);
    float em1r = wr - 1.0f, em1i = wi;
    float inv = 1.0f / fmaf(Ar, Ar, Ai * Ai);
    float qr = fmaf(em1r, Ar, em1i * Ai) * inv;
    float qi = fmaf(em1i, Ar, -(em1r * Ai)) * inv;
    float Cr = C_re[i], Ci = C_im[i];
    float c2r = 2.0f * (Cr * qr - Ci * qi);
    float c2i = 2.0f * (Cr * qi + Ci * qr);
    P[i]          = wr;
    P[HN + i]     = wi;
    P[2 * HN + i] = c2r;
    P[3 * HN + i] = c2i;

    // --- K table: K[h][tau] = sum_n Re(Ct2_n * w_n^tau)
    float pr = 1.0f, pi = 0.0f;
    for (int tau = 0; tau < 64; ++tau) {
        float term = c2r * pr - c2i * pi;
        #pragma unroll
        for (int m = 32; m > 0; m >>= 1) term += __shfl_xor(term, m, 64);
        if (lane == 0) ktab_s[wv][tau] = term;
        float nr = pr * wr - pi * wi, ni = pr * wi + pi * wr;
        pr = nr; pi = ni;
    }
    __syncthreads();

    // --- Toeplitz fill: Toep[h][t][j] = (j<=t) ? bf16(K[h][t-j]) : 0
    const int h0 = blockIdx.x * 4;
    #pragma unroll
    for (int r = 0; r < 8; ++r) {
        int c = t + r * 256;                  // uint4 chunk id, 2048/block
        int hh = c >> 9, rem = c & 511;
        int tt = rem >> 3, j0 = (rem & 7) * 8;
        u16 vv[8];
        #pragma unroll
        for (int jj = 0; jj < 8; ++jj) {
            int j = j0 + jj;
            vv[jj] = (j <= tt) ? f2b(ktab_s[hh][tt - j]) : (u16)0;
        }
        *(uint4*)&Toep_bf[((size_t)(h0 + hh) << 12) + (tt << 6) + j0] = *(uint4*)vv;
    }
}

// ---------------------------------------------------------------------------
// 2) Transpose x (B,L,H) fp32 -> XT (B,H,L) bf16
// ---------------------------------------------------------------------------
__global__ __launch_bounds__(256) void xtrans_kernel(
    const float* __restrict__ x, u16* __restrict__ XT)
{
    __shared__ float tile[32][33];
    int b  = blockIdx.z;
    int l0 = blockIdx.x * 32;
    int h0 = blockIdx.y * 32;
    int tx = threadIdx.x & 31;
    int ty = threadIdx.x >> 5;
    #pragma unroll
    for (int r = 0; r < 4; ++r)
        tile[ty + r * 8][tx] = x[((size_t)b * L_DIM + l0 + ty + r * 8) * H_DIM + h0 + tx];
    __syncthreads();
    #pragma unroll
    for (int r = 0; r < 4; ++r)
        XT[((size_t)b * H_DIM + h0 + ty + r * 8) * L_DIM + l0 + tx] = f2b(tile[tx][ty + r * 8]);
}

// ---------------------------------------------------------------------------
// 3) Chunked SSM via MFMA. One workgroup = (h, half of b). T=64, 32 chunks.
// ---------------------------------------------------------------------------
__global__ __launch_bounds__(256) void ssm_chunk_kernel(
    const u16* __restrict__ XT, const float* __restrict__ P,
    const u16* __restrict__ Toep_bf, const float* __restrict__ D_skip,
    u16* __restrict__ YT)
{
    __shared__ u16 U[128 * 72];      // [ncol][j], pad 72
    __shared__ u16 S[128 * 136];     // [ncol][2n], pad 136
    __shared__ u16 EVT[13312];       // union: E[128*72]=9216 | Toep[64*72]=4608 + V[64*136]=8704
    u16* E  = EVT;
    u16* Tp = EVT;
    u16* V  = EVT + 4608;

    const int h    = blockIdx.x;
    const int b0   = blockIdx.y * 4;
    const int t    = threadIdx.x;
    const int lane = t & 63;
    const int wv   = t >> 6;
    const int lm   = lane & 15, lq = lane >> 4;

    const int pidx = (h << 6) + lane;
    const float wr  = P[pidx],          wi  = P[HN + pidx];
    const float c2r = P[2 * HN + pidx], c2i = P[3 * HN + pidx];

    // stage U: 128 rows x 64 bf16, 16B chunks (coalesced), padded LDS rows
    #pragma unroll
    for (int r = 0; r < 4; ++r) {
        int idx = t + r * 256;
        int row = idx >> 3, ch = idx & 7;
        const u16* gp = XT + (((size_t)(b0 + (row >> 5)) * H_DIM + h) << 11)
                           + ((row & 31) << 6) + (ch << 3);
        *(uint4*)&U[row * 72 + ch * 8] = *(const uint4*)gp;
    }

    // base power w^(16*wv) for this wave
    float bwr, bwi;
    {
        float g16r = wr, g16i = wi;
        csq(g16r, g16i); csq(g16r, g16i); csq(g16r, g16i); csq(g16r, g16i); // w^16
        if (wv == 0)      { bwr = 1.0f; bwi = 0.0f; }
        else if (wv == 1) { bwr = g16r; bwi = g16i; }
        else if (wv == 2) { bwr = g16r; bwi = g16i; csq(bwr, bwi); }
        else {
            float g32r = g16r, g32i = g16i; csq(g32r, g32i);
            bwr = g32r * g16r - g32i * g16i;
            bwi = g32r * g16i + g32i * g16r;
        }
    }

    // fill E: E[2n][j]=Re(w^(63-j)), E[2n+1][j]=Im(w^(63-j))
    {
        float pr = bwr, pi = bwi;
        #pragma unroll
        for (int jk = 0; jk < 16; ++jk) {
            int k = (wv << 4) + jk;
            int j = 63 - k;
            E[(2 * lane) * 72 + j]     = f2b(pr);
            E[(2 * lane + 1) * 72 + j] = f2b(pi);
            float nr = pr * wr - pi * wi, ni = pr * wi + pi * wr;
            pr = nr; pi = ni;
        }
    }
    __syncthreads();

    // Phase A
    {
        const int wm = wv >> 1, wn = wv & 1;
        floatx4 acc[4][4] = {};
        #pragma unroll
        for (int ks = 0; ks < 2; ++ks) {
            bf16x8 af[4], bfv[4];
            #pragma unroll
            for (int i = 0; i < 4; ++i)
                af[i] = *(const bf16x8*)&E[(wm * 64 + i * 16 + lm) * 72 + ks * 32 + lq * 8];
            #pragma unroll
            for (int j = 0; j < 4; ++j)
                bfv[j] = *(const bf16x8*)&U[(wn * 64 + j * 16 + lm) * 72 + ks * 32 + lq * 8];
            #pragma unroll
            for (int i = 0; i < 4; ++i) {
                #pragma unroll
                for (int j = 0; j < 4; ++j)
                    acc[i][j] = __builtin_amdgcn_mfma_f32_16x16x32_bf16(af[i], bfv[j], acc[i][j], 0, 0, 0);
            }
        }
        #pragma unroll
        for (int i = 0; i < 4; ++i) {
            #pragma unroll
            for (int j = 0; j < 4; ++j) {
                int ncol = wn * 64 + j * 16 + lm;
                int m0   = wm * 64 + i * 16 + lq * 4;
                u16 pk[4];
                #pragma unroll
                for (int r = 0; r < 4; ++r) pk[r] = f2b(acc[i][j][r]);
                *(uint2*)&S[ncol * 136 + m0] = *(uint2*)pk;
            }
        }
    }
    __syncthreads();

    // fill V + stage Toep + chunk scan
    {
        float pr = bwr, pi = bwi;
        {
            float nr = pr * wr - pi * wi, ni = pr * wi + pi * wr;
            pr = nr; pi = ni;
        }
        #pragma unroll
        for (int jk = 1; jk <= 16; ++jk) {
            int tr = (wv << 4) + jk - 1;
            float qr = c2r * pr - c2i * pi;
            float qi = c2r * pi + c2i * pr;
            V[tr * 136 + 2 * lane]     = f2b(qr);
            V[tr * 136 + 2 * lane + 1] = f2b(-qi);
            float nr = pr * wr - pi * wi, ni = pr * wi + pi * wr;
            pr = nr; pi = ni;
        }
        #pragma unroll
        for (int r = 0; r < 2; ++r) {
            int idx = t + r * 256;
            int row = idx >> 3, ch = idx & 7;
            *(uint4*)&Tp[row * 72 + ch * 8] =
                *(const uint4*)&Toep_bf[((size_t)h << 12) + (row << 6) + (ch << 3)];
        }
        float wTr = wr, wTi = wi;
        csq(wTr, wTi); csq(wTr, wTi); csq(wTr, wTi);
        csq(wTr, wTi); csq(wTr, wTi); csq(wTr, wTi);   // w^64
        float Sr = 0.0f, Si = 0.0f;
        const int n2 = lane * 2;
        for (int c = 0; c < 32; ++c) {
            int base = (wv * 32 + c) * 136 + n2;
            unsigned lv = *(unsigned*)&S[base];
            float lr, li;
            unpack2(lv, lr, li);
            *(unsigned*)&S[base] = pack2(Sr, Si);
            float nSr = wTr * Sr - wTi * Si + lr;
            Si = wTr * Si + wTi * Sr + li;
            Sr = nSr;
        }
    }
    __syncthreads();

    // Phase C
    {
        const float Dh = D_skip[h];
        floatx4 acc[4][2] = {};
        #pragma unroll
        for (int ks = 0; ks < 6; ++ks) {
            bf16x8 af[4], bfv[2];
            if (ks < 2) {
                #pragma unroll
                for (int i = 0; i < 4; ++i)
                    af[i] = *(const bf16x8*)&Tp[(i * 16 + lm) * 72 + ks * 32 + lq * 8];
                #pragma unroll
                for (int j = 0; j < 2; ++j)
                    bfv[j] = *(const bf16x8*)&U[(wv * 32 + j * 16 + lm) * 72 + ks * 32 + lq * 8];
            } else {
                #pragma unroll
                for (int i = 0; i < 4; ++i)
                    af[i] = *(const bf16x8*)&V[(i * 16 + lm) * 136 + (ks - 2) * 32 + lq * 8];
                #pragma unroll
                for (int j = 0; j < 2; ++j)
                    bfv[j] = *(const bf16x8*)&S[(wv * 32 + j * 16 + lm) * 136 + (ks - 2) * 32 + lq * 8];
            }
            #pragma unroll
            for (int i = 0; i < 4; ++i) {
                #pragma unroll
                for (int j = 0; j < 2; ++j)
                    acc[i][j] = __builtin_amdgcn_mfma_f32_16x16x32_bf16(af[i], bfv[j], acc[i][j], 0, 0, 0);
            }
        }
        #pragma unroll
        for (int j = 0; j < 2; ++j) {
            int ncol = wv * 32 + j * 16 + lm;
            int bloc = ncol >> 5, c = ncol & 31;
            size_t gbase = (((size_t)(b0 + bloc) * H_DIM + h) << 11) + (c << 6);
            #pragma unroll
            for (int i = 0; i < 4; ++i) {
                int t0 = i * 16 + lq * 4;
                u16 upk[4];
                *(uint2*)upk = *(const uint2*)&U[ncol * 72 + t0];
                u16 opk[4];
                #pragma unroll
                for (int r = 0; r < 4; ++r) {
                    float uvv = b2f(upk[r]);
                    float yv = gelu_tanh_(fmaf(Dh, uvv, acc[i][j][r]));
                    opk[r] = f2b(yv);
                }
                *(uint2*)&YT[gbase + t0] = *(uint2*)opk;
            }
        }
    }
}

// ---------------------------------------------------------------------------
// 4) Transpose YT (B,H,L) bf16 -> Y (B,L,H) bf16
// ---------------------------------------------------------------------------
__global__ __launch_bounds__(256) void ytrans_kernel(
    const u16* __restrict__ YT, u16* __restrict__ Y)
{
    __shared__ u16 tile[32][33];
    int b  = blockIdx.z;
    int l0 = blockIdx.x * 32;
    int h0 = blockIdx.y * 32;
    int tx = threadIdx.x & 31;
    int ty = threadIdx.x >> 5;
    #pragma unroll
    for (int r = 0; r < 4; ++r)
        tile[ty + r * 8][tx] = YT[((size_t)b * H_DIM + h0 + ty + r * 8) * L_DIM + l0 + tx];
    __syncthreads();
    #pragma unroll
    for (int r = 0; r < 4; ++r)
        Y[((size_t)b * L_DIM + l0 + ty + r * 8) * H_DIM + h0 + tx] = tile[tx][ty + r * 8];
}

// ---------------------------------------------------------------------------
// stage a 128x32 bf16 tile into LDS via global_load_lds, 512 threads.
// LDS dest LINEAR; bank-swizzle via permuted GLOBAL source chunk
// (chunk' = chunk ^ ((row>>1)&3)); readers XOR the same way.
// ---------------------------------------------------------------------------
__device__ __forceinline__ void stage_tile_512(
    const u16* __restrict__ g, u16* lds, int row0, int k0)
{
    const int t = threadIdx.x;           // 0..511, one 16B chunk each
    const int row  = t >> 2;             // 0..127
    const int csrc = (t & 3) ^ ((t >> 3) & 3);
    const u16* gp = g + (size_t)(row0 + row) * 512 + k0 + csrc * 8;
    __builtin_amdgcn_global_load_lds(
        (const __attribute__((address_space(1))) unsigned int*)gp,
        (__attribute__((address_space(3))) unsigned int*)(lds + (size_t)t * 8),
        16, 0, 0);
}

// ---------------------------------------------------------------------------
// 5) GEMM1 + GLU + residual (dual-B). 512 threads (8 waves, 2m x 4n),
//    double-buffered 2-phase pipeline, swizzled LDS reads.
// ---------------------------------------------------------------------------
__global__ __launch_bounds__(512) void gemm1_glu_kernel(
    const u16* __restrict__ A, const u16* __restrict__ Wo,
    const float* __restrict__ bo, const float* __restrict__ x,
    u16* __restrict__ out)
{
    __shared__ u16 As[2][128 * 32];
    __shared__ u16 Ba[2][128 * 32];
    __shared__ u16 Bg[2][128 * 32];
    const int t    = threadIdx.x;
    const int lane = t & 63;
    const int wv   = t >> 6;             // 0..7
    const int wm   = wv >> 2, wn = wv & 3;
    const int lm   = lane & 15, lq = lane >> 4;
    const int sw   = (lq ^ ((lm >> 1) & 3)) * 8;
    const int m0   = blockIdx.x * 128, n0 = blockIdx.y * 128;
    floatx4 accA[4][2] = {};
    floatx4 accG[4][2] = {};

    stage_tile_512(A, As[0], m0, 0);
    stage_tile_512(Wo, Ba[0], n0, 0);
    stage_tile_512(Wo, Bg[0], 512 + n0, 0);
    __syncthreads();

    int cur = 0;
    for (int k0 = 32; k0 < 512; k0 += 32) {
        const int nx = cur ^ 1;
        stage_tile_512(A, As[nx], m0, k0);
        stage_tile_512(Wo, Ba[nx], n0, k0);
        stage_tile_512(Wo, Bg[nx], 512 + n0, k0);

        bf16x8 af[4], ba[2], bg[2];
        #pragma unroll
        for (int i = 0; i < 4; ++i)
            af[i] = *(const bf16x8*)&As[cur][(wm * 64 + i * 16 + lm) * 32 + sw];
        #pragma unroll
        for (int j = 0; j < 2; ++j) {
            ba[j] = *(const bf16x8*)&Ba[cur][(wn * 32 + j * 16 + lm) * 32 + sw];
            bg[j] = *(const bf16x8*)&Bg[cur][(wn * 32 + j * 16 + lm) * 32 + sw];
        }
        #pragma unroll
        for (int i = 0; i < 4; ++i) {
            #pragma unroll
            for (int j = 0; j < 2; ++j) {
                accA[i][j] = __builtin_amdgcn_mfma_f32_16x16x32_bf16(af[i], ba[j], accA[i][j], 0, 0, 0);
                accG[i][j] = __builtin_amdgcn_mfma_f32_16x16x32_bf16(af[i], bg[j], accG[i][j], 0, 0, 0);
            }
        }
        __syncthreads();
        cur = nx;
    }
    {
        bf16x8 af[4], ba[2], bg[2];
        #pragma unroll
        for (int i = 0; i < 4; ++i)
            af[i] = *(const bf16x8*)&As[cur][(wm * 64 + i * 16 + lm) * 32 + sw];
        #pragma unroll
        for (int j = 0; j < 2; ++j) {
            ba[j] = *(const bf16x8*)&Ba[cur][(wn * 32 + j * 16 + lm) * 32 + sw];
            bg[j] = *(const bf16x8*)&Bg[cur][(wn * 32 + j * 16 + lm) * 32 + sw];
        }
        #pragma unroll
        for (int i = 0; i < 4; ++i) {
            #pragma unroll
            for (int j = 0; j < 2; ++j) {
                accA[i][j] = __builtin_amdgcn_mfma_f32_16x16x32_bf16(af[i], ba[j], accA[i][j], 0, 0, 0);
                accG[i][j] = __builtin_amdgcn_mfma_f32_16x16x32_bf16(af[i], bg[j], accG[i][j], 0, 0, 0);
            }
        }
    }
    #pragma unroll
    for (int j = 0; j < 2; ++j) {
        int n = n0 + wn * 32 + j * 16 + lm;
        float bav = bo[n], bgv = bo[512 + n];
        #pragma unroll
        for (int i = 0; i < 4; ++i) {
            #pragma unroll
            for (int r = 0; r < 4; ++r) {
                int m = m0 + wm * 64 + i * 16 + lq * 4 + r;
                float av = accA[i][j][r] + bav;
                float gv = accG[i][j][r] + bgv;
                float xv = x[(size_t)m * 512 + n];
                out[(size_t)m * 512 + n] = f2b(fmaf(av, sigmoidf_(gv), xv));
            }
        }
    }
}

// ---------------------------------------------------------------------------
// 6) MFMA GEMM + ReLU: r3 = relu(A[M,512]·W1[512,512]^T + bias)
//    512 threads (8 waves, 2m x 4n), double-buffered, swizzled LDS reads.
// ---------------------------------------------------------------------------
__global__ __launch_bounds__(512) void gemm_relu_kernel(
    const u16* __restrict__ A, const u16* __restrict__ Bw,
    const float* __restrict__ bias, u16* __restrict__ C)
{
    __shared__ u16 As[2][128 * 32];
    __shared__ u16 Bs[2][128 * 32];
    const int t    = threadIdx.x;
    const int lane = t & 63;
    const int wv   = t >> 6;
    const int wm   = wv >> 2, wn = wv & 3;
    const int lm   = lane & 15, lq = lane >> 4;
    const int sw   = (lq ^ ((lm >> 1) & 3)) * 8;
    const int m0   = blockIdx.x * 128, n0 = blockIdx.y * 128;
    floatx4 acc[4][2] = {};

    stage_tile_512(A, As[0], m0, 0);
    stage_tile_512(Bw, Bs[0], n0, 0);
    __syncthreads();

    int cur = 0;
    for (int k0 = 32; k0 < 512; k0 += 32) {
        const int nx = cur ^ 1;
        stage_tile_512(A, As[nx], m0, k0);
        stage_tile_512(Bw, Bs[nx], n0, k0);

        bf16x8 af[4], bfr[2];
        #pragma unroll
        for (int i = 0; i < 4; ++i)
            af[i] = *(const bf16x8*)&As[cur][(wm * 64 + i * 16 + lm) * 32 + sw];
        #pragma unroll
        for (int j = 0; j < 2; ++j)
            bfr[j] = *(const bf16x8*)&Bs[cur][(wn * 32 + j * 16 + lm) * 32 + sw];
        #pragma unroll
        for (int i = 0; i < 4; ++i) {
            #pragma unroll
            for (int j = 0; j < 2; ++j)
                acc[i][j] = __builtin_amdgcn_mfma_f32_16x16x32_bf16(af[i], bfr[j], acc[i][j], 0, 0, 0);
        }
        __syncthreads();
        cur = nx;
    }
    {
        bf16x8 af[4], bfr[2];
        #pragma unroll
        for (int i = 0; i < 4; ++i)
            af[i] = *(const bf16x8*)&As[cur][(wm * 64 + i * 16 + lm) * 32 + sw];
        #pragma unroll
        for (int j = 0; j < 2; ++j)
            bfr[j] = *(const bf16x8*)&Bs[cur][(wn * 32 + j * 16 + lm) * 32 + sw];
        #pragma unroll
        for (int i = 0; i < 4; ++i) {
            #pragma unroll
            for (int j = 0; j < 2; ++j)
                acc[i][j] = __builtin_amdgcn_mfma_f32_16x16x32_bf16(af[i], bfr[j], acc[i][j], 0, 0, 0);
        }
    }
    #pragma unroll
    for (int j = 0; j < 2; ++j) {
        int n = n0 + wn * 32 + j * 16 + lm;
        float bv = bias[n];
        #pragma unroll
        for (int i = 0; i < 4; ++i) {
            #pragma unroll
            for (int r = 0; r < 4; ++r) {
                int m = m0 + wm * 64 + i * 16 + lq * 4 + r;
                float v = fmaxf(acc[i][j][r] + bv, 0.0f);
                C[(size_t)m * 512 + n] = f2b(v);
            }
        }
    }
}

// ---------------------------------------------------------------------------
// 7) FUSED GEMM2 + residual + LayerNorm2 -> fp32 out.
//    Full-N stripe: tile M=32 x N=512 so LN rows are block-complete.
//    512 threads = 8 waves, each wave owns a 64-wide n-stripe (j=0..3),
//    2 m-fragments. LDS: A 2x2KB + B 2x32KB + lnred 2KB = 70KB -> 2 blk/CU.
//    A (h1) fetched ONCE (vs 4x in tiled layout); W2 is L2-resident.
// ---------------------------------------------------------------------------
__global__ __launch_bounds__(512) void gemm2_ln_kernel(
    const u16* __restrict__ A, const u16* __restrict__ Bw,
    const float* __restrict__ bias, const u16* __restrict__ res,
    const float* __restrict__ gamma, const float* __restrict__ beta,
    float* __restrict__ out)
{
    __shared__ u16 As[2][32 * 32];
    __shared__ u16 Bs[2][512 * 32];
    __shared__ float2 lnred[32 * 8];
    const int t    = threadIdx.x;
    const int lane = t & 63;
    const int wv   = t >> 6;
    const int lm   = lane & 15, lq = lane >> 4;
    const int sw   = (lq ^ ((lm >> 1) & 3)) * 8;
    const int m0   = blockIdx.x * 32;
    floatx4 acc[2][4] = {};

    const int csrc = (t & 3) ^ ((t >> 3) & 3);

    // prologue stage k=0
    {
        #pragma unroll
        for (int r = 0; r < 4; ++r) {
            int row = (t >> 2) + r * 128;
            const u16* gp = Bw + (size_t)row * 512 + csrc * 8;
            __builtin_amdgcn_global_load_lds(
                (const __attribute__((address_space(1))) unsigned int*)gp,
                (__attribute__((address_space(3))) unsigned int*)(&Bs[0][0] + (size_t)t * 8 + (size_t)r * 4096),
                16, 0, 0);
        }
        if (t < 128) {
            int row = t >> 2;
            const u16* gp = A + (size_t)(m0 + row) * 512 + csrc * 8;
            __builtin_amdgcn_global_load_lds(
                (const __attribute__((address_space(1))) unsigned int*)gp,
                (__attribute__((address_space(3))) unsigned int*)(&As[0][0] + (size_t)t * 8),
                16, 0, 0);
        }
    }
    __syncthreads();

    int cur = 0;
    for (int k0 = 32; k0 < 512; k0 += 32) {
        const int nx = cur ^ 1;
        // prefetch next K-tile
        #pragma unroll
        for (int r = 0; r < 4; ++r) {
            int row = (t >> 2) + r * 128;
            const u16* gp = Bw + (size_t)row * 512 + k0 + csrc * 8;
            __builtin_amdgcn_global_load_lds(
                (const __attribute__((address_space(1))) unsigned int*)gp,
                (__attribute__((address_space(3))) unsigned int*)(&Bs[nx][0] + (size_t)t * 8 + (size_t)r * 4096),
                16, 0, 0);
        }
        if (t < 128) {
            int row = t >> 2;
            const u16* gp = A + (size_t)(m0 + row) * 512 + k0 + csrc * 8;
            __builtin_amdgcn_global_load_lds(
                (const __attribute__((address_space(1))) unsigned int*)gp,
                (__attribute__((address_space(3))) unsigned int*)(&As[nx][0] + (size_t)t * 8),
                16, 0, 0);
        }

        bf16x8 af[2], bfr[4];
        #pragma unroll
        for (int i = 0; i < 2; ++i)
            af[i] = *(const bf16x8*)&As[cur][(i * 16 + lm) * 32 + sw];
        #pragma unroll
        for (int j = 0; j < 4; ++j)
            bfr[j] = *(const bf16x8*)&Bs[cur][(wv * 64 + j * 16 + lm) * 32 + sw];
        #pragma unroll
        for (int i = 0; i < 2; ++i) {
            #pragma unroll
            for (int j = 0; j < 4; ++j)
                acc[i][j] = __builtin_amdgcn_mfma_f32_16x16x32_bf16(af[i], bfr[j], acc[i][j], 0, 0, 0);
        }
        __syncthreads();
        cur = nx;
    }
    // final K-tile
    {
        bf16x8 af[2], bfr[4];
        #pragma unroll
        for (int i = 0; i < 2; ++i)
            af[i] = *(const bf16x8*)&As[cur][(i * 16 + lm) * 32 + sw];
        #pragma unroll
        for (int j = 0; j < 4; ++j)
            bfr[j] = *(const bf16x8*)&Bs[cur][(wv * 64 + j * 16 + lm) * 32 + sw];
        #pragma unroll
        for (int i = 0; i < 2; ++i) {
            #pragma unroll
            for (int j = 0; j < 4; ++j)
                acc[i][j] = __builtin_amdgcn_mfma_f32_16x16x32_bf16(af[i], bfr[j], acc[i][j], 0, 0, 0);
        }
    }

    // epilogue: z = acc + bias + residual, then rowwise LN over N=512
    float bv[4], gv[4], btv[4];
    #pragma unroll
    for (int j = 0; j < 4; ++j) {
        int n = wv * 64 + j * 16 + lm;
        bv[j]  = bias[n];
        gv[j]  = gamma[n];
        btv[j] = beta[n];
    }
    #pragma unroll
    for (int i = 0; i < 2; ++i) {
        #pragma unroll
        for (int j = 0; j < 4; ++j) {
            int n = wv * 64 + j * 16 + lm;
            #pragma unroll
            for (int r = 0; r < 4; ++r) {
                int m = m0 + i * 16 + lq * 4 + r;
                acc[i][j][r] += bv[j] + b2f(res[(size_t)m * 512 + n]);
            }
        }
    }
    // per-row partials (this wave's 64-n slice), reduce across lm lanes
    #pragma unroll
    for (int i = 0; i < 2; ++i) {
        #pragma unroll
        for (int r = 0; r < 4; ++r) {
            float s  = acc[i][0][r] + acc[i][1][r] + acc[i][2][r] + acc[i][3][r];
            float sq = acc[i][0][r] * acc[i][0][r] + acc[i][1][r] * acc[i][1][r]
                     + acc[i][2][r] * acc[i][2][r] + acc[i][3][r] * acc[i][3][r];
            #pragma unroll
            for (int msk = 1; msk < 16; msk <<= 1) {
                s  += __shfl_xor(s, msk, 64);
                sq += __shfl_xor(sq, msk, 64);
            }
            if (lm == 0) {
                float2 p; p.x = s; p.y = sq;
                lnred[(i * 16 + lq * 4 + r) * 8 + wv] = p;
            }
        }
    }
    __syncthreads();
    #pragma unroll
    for (int i = 0; i < 2; ++i) {
        #pragma unroll
        for (int r = 0; r < 4; ++r) {
            int row = i * 16 + lq * 4 + r;
            float s = 0.0f, sq = 0.0f;
            #pragma unroll
            for (int w = 0; w < 8; ++w) {
                float2 p = lnred[row * 8 + w];
                s += p.x; sq += p.y;
            }
            float mu  = s * (1.0f / 512.0f);
            float var = sq * (1.0f / 512.0f) - mu * mu;
            float rs  = rsqrtf(var + 1e-5f);
            #pragma unroll
            for (int j = 0; j < 4; ++j) {
                int n = wv * 64 + j * 16 + lm;
                out[(size_t)(m0 + row) * 512 + n] = fmaf((acc[i][j][r] - mu) * rs, gv[j], btv[j]);
            }
        }
    }
}

// ---------------------------------------------------------------------------
// 8) LayerNorm over H=512; bf16 in, bf16 out (LN1)
// ---------------------------------------------------------------------------
__global__ __launch_bounds__(256) void ln_bf_kernel(
    const u16* __restrict__ in,
    const float* __restrict__ gamma, const float* __restrict__ beta,
    u16* __restrict__ outb)
{
    int w    = threadIdx.x >> 6;
    int lane = threadIdx.x & 63;
    size_t row  = (size_t)blockIdx.x * 4 + w;
    size_t base = row * 512 + lane * 8;
    uint4 raw = *(const uint4*)(in + base);
    float v[8];
    unpack2(raw.x, v[0], v[1]); unpack2(raw.y, v[2], v[3]);
    unpack2(raw.z, v[4], v[5]); unpack2(raw.w, v[6], v[7]);
    float s = 0.0f, sq = 0.0f;
    #pragma unroll
    for (int i = 0; i < 8; ++i) { s += v[i]; sq = fmaf(v[i], v[i], sq); }
    #pragma unroll
    for (int m = 32; m > 0; m >>= 1) {
        s  += __shfl_xor(s, m, 64);
        sq += __shfl_xor(sq, m, 64);
    }
    float mu  = s * (1.0f / 512.0f);
    float var = sq * (1.0f / 512.0f) - mu * mu;
    float rs  = rsqrtf(var + 1e-5f);
    float g[8], bt[8];
    *(float4*)&g[0]  = *(const float4*)(gamma + lane * 8);
    *(float4*)&g[4]  = *(const float4*)(gamma + lane * 8 + 4);
    *(float4*)&bt[0] = *(const float4*)(beta + lane * 8);
    *(float4*)&bt[4] = *(const float4*)(beta + lane * 8 + 4);
    float o[8];
    #pragma unroll
    for (int i = 0; i < 8; ++i)
        o[i] = fmaf((v[i] - mu) * rs, g[i], bt[i]);
    uint4 p;
    p.x = pack2(o[0], o[1]); p.y = pack2(o[2], o[3]);
    p.z = pack2(o[4], o[5]); p.w = pack2(o[6], o[7]);
    *(uint4*)(outb + base) = p;
}

// ---------------------------------------------------------------------------
extern "C" void kernel_launch(void* const* d_in, const int* in_sizes, int n_in,
                              void* d_out, int out_size, void* d_ws, size_t ws_size,
                              hipStream_t stream)
{
    (void)in_sizes; (void)n_in; (void)out_size; (void)ws_size;
    const float* x      = (const float*)d_in[0];
    const float* log_dt = (const float*)d_in[1];
    const float* A_re   = (const float*)d_in[2];
    const float* A_im   = (const float*)d_in[3];
    const float* C_re   = (const float*)d_in[4];
    const float* C_im   = (const float*)d_in[5];
    const float* D_skip = (const float*)d_in[6];
    const float* W_out  = (const float*)d_in[7];
    const float* b_out  = (const float*)d_in[8];
    const float* g1     = (const float*)d_in[9];
    const float* beta1  = (const float*)d_in[10];
    const float* g2     = (const float*)d_in[11];
    const float* beta2  = (const float*)d_in[12];
    const float* W1     = (const float*)d_in[13];
    const float* bc1    = (const float*)d_in[14];
    const float* W2     = (const float*)d_in[15];
    const float* bc2    = (const float*)d_in[16];
    float* out = (float*)d_out;

    // workspace: P 512K | (hole 128K) | Toep_bf 4M | weights 2M | r1/r2/r3 bf16 BLH
    char*  wsb    = (char*)d_ws;
    float* P      = (float*)wsb;
    u16*   Toep   = (u16*)(wsb + 4 * HN * 4 + 512 * 64 * 4);
    u16*   Wobf   = Toep + 512 * 4096;
    u16*   W1bf   = Wobf + 1024 * 512;
    u16*   W2bf   = W1bf + 512 * 512;
    u16*   r1     = W2bf + 512 * 512;   // XT -> x1n_bf
    u16*   r2     = r1 + BLH;           // YT -> x1pre_bf
    u16*   r3     = r2 + BLH;           // Y  -> h1_bf

    cast3_kernel<<<1024, 256, 0, stream>>>(W_out, W1, W2, Wobf, W1bf, W2bf);
    params_kernel<<<128, 256, 0, stream>>>(log_dt, A_re, A_im, C_re, C_im, P, Toep);
    xtrans_kernel<<<dim3(L_DIM / 32, H_DIM / 32, B_DIM), 256, 0, stream>>>(x, r1);
    ssm_chunk_kernel<<<dim3(H_DIM, 2), 256, 0, stream>>>(r1, P, Toep, D_skip, r2);
    ytrans_kernel<<<dim3(L_DIM / 32, H_DIM / 32, B_DIM), 256, 0, stream>>>(r2, r3);
    gemm1_glu_kernel<<<dim3(M_DIM / 128, 4), 512, 0, stream>>>(r3, Wobf, b_out, x, r2);
    ln_bf_kernel<<<M_DIM / 4, 256, 0, stream>>>(r2, g1, beta1, r1);
    gemm_relu_kernel<<<dim3(M_DIM / 128, 4), 512, 0, stream>>>(r1, W1bf, bc1, r3);
    gemm2_ln_kernel<<<M_DIM / 32, 512, 0, stream>>>(r3, W2bf, bc2, r1, g2, beta2, out);
}

// Round 5
// 240.083 us; speedup vs baseline: 1.1729x; 1.0208x over previous
//
#include <hip/hip_runtime.h>
#include <cstddef>
#include <cstdint>

#define B_DIM 8
#define L_DIM 2048
#define H_DIM 512
#define N_DIM 64
#define HN (H_DIM * N_DIM)          // 32768
#define BLH (B_DIM * L_DIM * H_DIM) // 8388608
#define M_DIM (B_DIM * L_DIM)       // 16384

typedef unsigned short u16;
typedef short bf16x8 __attribute__((ext_vector_type(8)));
typedef float floatx4 __attribute__((ext_vector_type(4)));

__device__ __forceinline__ float sigmoidf_(float v) {
    return 1.0f / (1.0f + __expf(-v));
}

// jax.nn.gelu default: approximate=True (tanh form)
__device__ __forceinline__ float gelu_tanh_(float x) {
    float x3 = x * x * x;
    float z = 0.7978845608028654f * fmaf(0.044715f, x3, x);
    float e = __expf(-2.0f * fabsf(z));
    float th = (1.0f - e) / (1.0f + e);
    th = copysignf(th, z);
    return 0.5f * x * (1.0f + th);
}

__device__ __forceinline__ u16 f2b(float f) {
    unsigned u = __float_as_uint(f);
    unsigned r = (u + 0x7fffu + ((u >> 16) & 1u)) >> 16;
    return (u16)r;
}
__device__ __forceinline__ float b2f(u16 u) {
    return __uint_as_float(((unsigned)u) << 16);
}
__device__ __forceinline__ void unpack2(unsigned u, float& a, float& b) {
    a = __uint_as_float(u << 16);
    b = __uint_as_float(u & 0xffff0000u);
}
__device__ __forceinline__ unsigned pack2(float a, float b) {
    return (unsigned)f2b(a) | ((unsigned)f2b(b) << 16);
}

// complex helpers
__device__ __forceinline__ void csq(float& r, float& i) {
    float nr = r * r - i * i;
    i = 2.0f * r * i;
    r = nr;
}

// ---------------------------------------------------------------------------
// 0) SETUP (one launch, block-partitioned):
//    [0,8192)     xtrans: x (B,L,H) fp32 -> XT (B,H,L) bf16
//    [8192,9216)  weight casts: Wo->bf16, W1*g1->bf16 (LN1 fold), W2->bf16
//    [9216,9344)  SSM params P + Ktab(LDS) + Toeplitz fill
//    [9344,9472)  LN1-fold column sums: c1[f]=sum_n W1[f][n]g1[n], c2=..beta1
// ---------------------------------------------------------------------------
__global__ __launch_bounds__(256) void setup_kernel(
    const float* __restrict__ x, const float* __restrict__ W_out,
    const float* __restrict__ W1, const float* __restrict__ W2,
    const float* __restrict__ log_dt, const float* __restrict__ A_re,
    const float* __restrict__ A_im, const float* __restrict__ C_re,
    const float* __restrict__ C_im, const float* __restrict__ g1,
    const float* __restrict__ beta1,
    u16* __restrict__ XT, u16* __restrict__ Wobf, u16* __restrict__ W1gbf,
    u16* __restrict__ W2bf, float* __restrict__ P, u16* __restrict__ Toep_bf,
    float* __restrict__ c1, float* __restrict__ c2)
{
    __shared__ float tile[32][33];
    __shared__ float ktab_s[4][64];
    const int bid = blockIdx.x;
    const int t   = threadIdx.x;

    if (bid < 8192) {
        // ---- xtrans
        int b  = bid >> 10;
        int hy = (bid >> 6) & 15;
        int lx = bid & 63;
        int l0 = lx * 32, h0 = hy * 32;
        int tx = t & 31, ty = t >> 5;
        #pragma unroll
        for (int r = 0; r < 4; ++r)
            tile[ty + r * 8][tx] = x[((size_t)b * L_DIM + l0 + ty + r * 8) * H_DIM + h0 + tx];
        __syncthreads();
        #pragma unroll
        for (int r = 0; r < 4; ++r)
            XT[(((size_t)b * H_DIM + h0 + ty + r * 8) << 11) + l0 + tx] = f2b(tile[tx][ty + r * 8]);
    } else if (bid < 9216) {
        // ---- weight casts
        int off = bid - 8192;
        if (off < 512) {
            int i = off * 256 + t;
            float4 v = *(const float4*)(W_out + (size_t)i * 4);
            uint2 p; p.x = pack2(v.x, v.y); p.y = pack2(v.z, v.w);
            *(uint2*)(Wobf + (size_t)i * 4) = p;
        } else if (off < 768) {
            int i = (off - 512) * 256 + t;
            float4 v = *(const float4*)(W1 + (size_t)i * 4);
            int n = (i * 4) & 511;
            float4 g = *(const float4*)(g1 + n);
            uint2 p; p.x = pack2(v.x * g.x, v.y * g.y);
            p.y = pack2(v.z * g.z, v.w * g.w);
            *(uint2*)(W1gbf + (size_t)i * 4) = p;
        } else {
            int i = (off - 768) * 256 + t;
            float4 v = *(const float4*)(W2 + (size_t)i * 4);
            uint2 p; p.x = pack2(v.x, v.y); p.y = pack2(v.z, v.w);
            *(uint2*)(W2bf + (size_t)i * 4) = p;
        }
    } else if (bid < 9344) {
        // ---- SSM params + Ktab + Toeplitz
        const int wv = t >> 6, lane = t & 63;
        const int i = (bid - 9216) * 256 + t;
        const int h = i >> 6;
        float dt = expf(log_dt[h]);
        float Ar = A_re[i], Ai = A_im[i];
        float ar = dt * Ar, ai = dt * Ai;
        float e = expf(ar);
        float wr = e * cosf(ai);
        float wi = e * sinf(ai);
        float em1r = wr - 1.0f, em1i = wi;
        float inv = 1.0f / fmaf(Ar, Ar, Ai * Ai);
        float qr = fmaf(em1r, Ar, em1i * Ai) * inv;
        float qi = fmaf(em1i, Ar, -(em1r * Ai)) * inv;
        float Cr = C_re[i], Ci = C_im[i];
        float c2r = 2.0f * (Cr * qr - Ci * qi);
        float c2i = 2.0f * (Cr * qi + Ci * qr);
        P[i]          = wr;
        P[HN + i]     = wi;
        P[2 * HN + i] = c2r;
        P[3 * HN + i] = c2i;

        float pr = 1.0f, pi = 0.0f;
        for (int tau = 0; tau < 64; ++tau) {
            float term = c2r * pr - c2i * pi;
            #pragma unroll
            for (int m = 32; m > 0; m >>= 1) term += __shfl_xor(term, m, 64);
            if (lane == 0) ktab_s[wv][tau] = term;
            float nr = pr * wr - pi * wi, ni = pr * wi + pi * wr;
            pr = nr; pi = ni;
        }
        __syncthreads();

        const int h0 = (bid - 9216) * 4;
        #pragma unroll
        for (int r = 0; r < 8; ++r) {
            int c = t + r * 256;
            int hh = c >> 9, rem = c & 511;
            int tt = rem >> 3, j0 = (rem & 7) * 8;
            u16 vv[8];
            #pragma unroll
            for (int jj = 0; jj < 8; ++jj) {
                int j = j0 + jj;
                vv[jj] = (j <= tt) ? f2b(ktab_s[hh][tt - j]) : (u16)0;
            }
            *(uint4*)&Toep_bf[((size_t)(h0 + hh) << 12) + (tt << 6) + j0] = *(uint4*)vv;
        }
    } else {
        // ---- LN1-fold column sums over n for W1 row f
        int f = (bid - 9344) * 4 + (t >> 6);
        int lane = t & 63;
        int n = lane * 8;
        float4 w0 = *(const float4*)(W1 + (size_t)f * 512 + n);
        float4 w1v = *(const float4*)(W1 + (size_t)f * 512 + n + 4);
        float4 ga = *(const float4*)(g1 + n);
        float4 gb = *(const float4*)(g1 + n + 4);
        float4 b0 = *(const float4*)(beta1 + n);
        float4 b1 = *(const float4*)(beta1 + n + 4);
        float s1 = w0.x * ga.x + w0.y * ga.y + w0.z * ga.z + w0.w * ga.w
                 + w1v.x * gb.x + w1v.y * gb.y + w1v.z * gb.z + w1v.w * gb.w;
        float s2 = w0.x * b0.x + w0.y * b0.y + w0.z * b0.z + w0.w * b0.w
                 + w1v.x * b1.x + w1v.y * b1.y + w1v.z * b1.z + w1v.w * b1.w;
        #pragma unroll
        for (int m = 32; m > 0; m >>= 1) {
            s1 += __shfl_xor(s1, m, 64);
            s2 += __shfl_xor(s2, m, 64);
        }
        if (lane == 0) { c1[f] = s1; c2[f] = s2; }
    }
}

// ---------------------------------------------------------------------------
// 3) Chunked SSM via MFMA. One workgroup = (h, half of b). T=64, 32 chunks.
// ---------------------------------------------------------------------------
__global__ __launch_bounds__(256) void ssm_chunk_kernel(
    const u16* __restrict__ XT, const float* __restrict__ P,
    const u16* __restrict__ Toep_bf, const float* __restrict__ D_skip,
    u16* __restrict__ YT)
{
    __shared__ u16 U[128 * 72];      // [ncol][j], pad 72
    __shared__ u16 S[128 * 136];     // [ncol][2n], pad 136
    __shared__ u16 EVT[13312];       // union: E[128*72]=9216 | Toep[64*72]=4608 + V[64*136]=8704
    u16* E  = EVT;
    u16* Tp = EVT;
    u16* V  = EVT + 4608;

    const int h    = blockIdx.x;
    const int b0   = blockIdx.y * 4;
    const int t    = threadIdx.x;
    const int lane = t & 63;
    const int wv   = t >> 6;
    const int lm   = lane & 15, lq = lane >> 4;

    const int pidx = (h << 6) + lane;
    const float wr  = P[pidx],          wi  = P[HN + pidx];
    const float c2r = P[2 * HN + pidx], c2i = P[3 * HN + pidx];

    // stage U: 128 rows x 64 bf16, 16B chunks (coalesced), padded LDS rows
    #pragma unroll
    for (int r = 0; r < 4; ++r) {
        int idx = t + r * 256;
        int row = idx >> 3, ch = idx & 7;
        const u16* gp = XT + (((size_t)(b0 + (row >> 5)) * H_DIM + h) << 11)
                           + ((row & 31) << 6) + (ch << 3);
        *(uint4*)&U[row * 72 + ch * 8] = *(const uint4*)gp;
    }

    // base power w^(16*wv) for this wave
    float bwr, bwi;
    {
        float g16r = wr, g16i = wi;
        csq(g16r, g16i); csq(g16r, g16i); csq(g16r, g16i); csq(g16r, g16i); // w^16
        if (wv == 0)      { bwr = 1.0f; bwi = 0.0f; }
        else if (wv == 1) { bwr = g16r; bwi = g16i; }
        else if (wv == 2) { bwr = g16r; bwi = g16i; csq(bwr, bwi); }
        else {
            float g32r = g16r, g32i = g16i; csq(g32r, g32i);
            bwr = g32r * g16r - g32i * g16i;
            bwi = g32r * g16i + g32i * g16r;
        }
    }

    // fill E: E[2n][j]=Re(w^(63-j)), E[2n+1][j]=Im(w^(63-j))
    {
        float pr = bwr, pi = bwi;
        #pragma unroll
        for (int jk = 0; jk < 16; ++jk) {
            int k = (wv << 4) + jk;
            int j = 63 - k;
            E[(2 * lane) * 72 + j]     = f2b(pr);
            E[(2 * lane + 1) * 72 + j] = f2b(pi);
            float nr = pr * wr - pi * wi, ni = pr * wi + pi * wr;
            pr = nr; pi = ni;
        }
    }
    __syncthreads();

    // Phase A
    {
        const int wm = wv >> 1, wn = wv & 1;
        floatx4 acc[4][4] = {};
        #pragma unroll
        for (int ks = 0; ks < 2; ++ks) {
            bf16x8 af[4], bfv[4];
            #pragma unroll
            for (int i = 0; i < 4; ++i)
                af[i] = *(const bf16x8*)&E[(wm * 64 + i * 16 + lm) * 72 + ks * 32 + lq * 8];
            #pragma unroll
            for (int j = 0; j < 4; ++j)
                bfv[j] = *(const bf16x8*)&U[(wn * 64 + j * 16 + lm) * 72 + ks * 32 + lq * 8];
            #pragma unroll
            for (int i = 0; i < 4; ++i) {
                #pragma unroll
                for (int j = 0; j < 4; ++j)
                    acc[i][j] = __builtin_amdgcn_mfma_f32_16x16x32_bf16(af[i], bfv[j], acc[i][j], 0, 0, 0);
            }
        }
        #pragma unroll
        for (int i = 0; i < 4; ++i) {
            #pragma unroll
            for (int j = 0; j < 4; ++j) {
                int ncol = wn * 64 + j * 16 + lm;
                int m0   = wm * 64 + i * 16 + lq * 4;
                u16 pk[4];
                #pragma unroll
                for (int r = 0; r < 4; ++r) pk[r] = f2b(acc[i][j][r]);
                *(uint2*)&S[ncol * 136 + m0] = *(uint2*)pk;
            }
        }
    }
    __syncthreads();

    // fill V + stage Toep + chunk scan
    {
        float pr = bwr, pi = bwi;
        {
            float nr = pr * wr - pi * wi, ni = pr * wi + pi * wr;
            pr = nr; pi = ni;
        }
        #pragma unroll
        for (int jk = 1; jk <= 16; ++jk) {
            int tr = (wv << 4) + jk - 1;
            float qr = c2r * pr - c2i * pi;
            float qi = c2r * pi + c2i * pr;
            V[tr * 136 + 2 * lane]     = f2b(qr);
            V[tr * 136 + 2 * lane + 1] = f2b(-qi);
            float nr = pr * wr - pi * wi, ni = pr * wi + pi * wr;
            pr = nr; pi = ni;
        }
        #pragma unroll
        for (int r = 0; r < 2; ++r) {
            int idx = t + r * 256;
            int row = idx >> 3, ch = idx & 7;
            *(uint4*)&Tp[row * 72 + ch * 8] =
                *(const uint4*)&Toep_bf[((size_t)h << 12) + (row << 6) + (ch << 3)];
        }
        float wTr = wr, wTi = wi;
        csq(wTr, wTi); csq(wTr, wTi); csq(wTr, wTi);
        csq(wTr, wTi); csq(wTr, wTi); csq(wTr, wTi);   // w^64
        float Sr = 0.0f, Si = 0.0f;
        const int n2 = lane * 2;
        for (int c = 0; c < 32; ++c) {
            int base = (wv * 32 + c) * 136 + n2;
            unsigned lv = *(unsigned*)&S[base];
            float lr, li;
            unpack2(lv, lr, li);
            *(unsigned*)&S[base] = pack2(Sr, Si);
            float nSr = wTr * Sr - wTi * Si + lr;
            Si = wTr * Si + wTi * Sr + li;
            Sr = nSr;
        }
    }
    __syncthreads();

    // Phase C
    {
        const float Dh = D_skip[h];
        floatx4 acc[4][2] = {};
        #pragma unroll
        for (int ks = 0; ks < 6; ++ks) {
            bf16x8 af[4], bfv[2];
            if (ks < 2) {
                #pragma unroll
                for (int i = 0; i < 4; ++i)
                    af[i] = *(const bf16x8*)&Tp[(i * 16 + lm) * 72 + ks * 32 + lq * 8];
                #pragma unroll
                for (int j = 0; j < 2; ++j)
                    bfv[j] = *(const bf16x8*)&U[(wv * 32 + j * 16 + lm) * 72 + ks * 32 + lq * 8];
            } else {
                #pragma unroll
                for (int i = 0; i < 4; ++i)
                    af[i] = *(const bf16x8*)&V[(i * 16 + lm) * 136 + (ks - 2) * 32 + lq * 8];
                #pragma unroll
                for (int j = 0; j < 2; ++j)
                    bfv[j] = *(const bf16x8*)&S[(wv * 32 + j * 16 + lm) * 136 + (ks - 2) * 32 + lq * 8];
            }
            #pragma unroll
            for (int i = 0; i < 4; ++i) {
                #pragma unroll
                for (int j = 0; j < 2; ++j)
                    acc[i][j] = __builtin_amdgcn_mfma_f32_16x16x32_bf16(af[i], bfv[j], acc[i][j], 0, 0, 0);
            }
        }
        #pragma unroll
        for (int j = 0; j < 2; ++j) {
            int ncol = wv * 32 + j * 16 + lm;
            int bloc = ncol >> 5, c = ncol & 31;
            size_t gbase = (((size_t)(b0 + bloc) * H_DIM + h) << 11) + (c << 6);
            #pragma unroll
            for (int i = 0; i < 4; ++i) {
                int t0 = i * 16 + lq * 4;
                u16 upk[4];
                *(uint2*)upk = *(const uint2*)&U[ncol * 72 + t0];
                u16 opk[4];
                #pragma unroll
                for (int r = 0; r < 4; ++r) {
                    float uvv = b2f(upk[r]);
                    float yv = gelu_tanh_(fmaf(Dh, uvv, acc[i][j][r]));
                    opk[r] = f2b(yv);
                }
                *(uint2*)&YT[gbase + t0] = *(uint2*)opk;
            }
        }
    }
}

// ---------------------------------------------------------------------------
// stage a 128x32 bf16 tile into LDS via global_load_lds, 512 threads.
// LDS dest LINEAR; bank-swizzle via permuted GLOBAL source chunk
// (chunk' = chunk ^ ((row>>1)&3)); readers XOR the same way.
// ---------------------------------------------------------------------------
__device__ __forceinline__ void stage_tile_512(
    const u16* __restrict__ g, u16* lds, int row0, int k0)
{
    const int t = threadIdx.x;           // 0..511, one 16B chunk each
    const int row  = t >> 2;             // 0..127
    const int csrc = (t & 3) ^ ((t >> 3) & 3);
    const u16* gp = g + (size_t)(row0 + row) * 512 + k0 + csrc * 8;
    __builtin_amdgcn_global_load_lds(
        (const __attribute__((address_space(1))) unsigned int*)gp,
        (__attribute__((address_space(3))) unsigned int*)(lds + (size_t)t * 8),
        16, 0, 0);
}

// A-tile from YT (B,H,L): thread reads 8 consecutive l for one h(=k), then
// transposes into As[l][k] via 8 offset-immediate ds_write_b16.
// Swizzle on chunk: c_store = kc ^ ((row>>3)&3)  (row>>3 == lc here).
__device__ __forceinline__ uint4 ldA_yt(
    const u16* __restrict__ YT, int b, int l0, int k0)
{
    const int k  = threadIdx.x >> 4;
    const int lc = threadIdx.x & 15;
    return *(const uint4*)(YT + (((size_t)(b * 512 + k0 + k)) << 11) + l0 + lc * 8);
}
__device__ __forceinline__ void dswA(u16* lds, uint4 av)
{
    const int k  = threadIdx.x >> 4;
    const int lc = threadIdx.x & 15;
    u16* p = lds + (lc * 8) * 32 + (((k >> 3) ^ (lc & 3)) << 3) + (k & 7);
    const u16* s = (const u16*)&av;
    #pragma unroll
    for (int j = 0; j < 8; ++j) p[j * 32] = s[j];
}

// ---------------------------------------------------------------------------
// 5) GEMM1 + GLU + residual (dual-B) reading A DIRECTLY from YT (ytrans
//    eliminated), plus LN1 row-stats (sum, sumsq) side-output per n0-block.
//    512 threads (8 waves, 2m x 4n), double-buffered 2-phase pipeline.
// ---------------------------------------------------------------------------
__global__ __launch_bounds__(512) void gemm1_glu_kernel(
    const u16* __restrict__ YT, const u16* __restrict__ Wo,
    const float* __restrict__ bo, const float* __restrict__ x,
    u16* __restrict__ out, float2* __restrict__ Pstats)
{
    __shared__ u16 As[2][128 * 32];
    __shared__ u16 Ba[2][128 * 32];
    __shared__ u16 Bg[2][128 * 32];
    __shared__ float2 red1[128][4];
    const int t    = threadIdx.x;
    const int lane = t & 63;
    const int wv   = t >> 6;             // 0..7
    const int wm   = wv >> 2, wn = wv & 3;
    const int lm   = lane & 15, lq = lane >> 4;
    const int sw   = (lq ^ ((lm >> 1) & 3)) * 8;   // B-side read swizzle
    const int m0   = blockIdx.x * 128, n0 = blockIdx.y * 128;
    const int b    = m0 >> 11;
    const int l0   = m0 & 2047;
    floatx4 accA[4][2] = {};
    floatx4 accG[4][2] = {};

    // A-side read swizzle per i (row>>3 bits reduce to lane bits)
    int swA[4];
    #pragma unroll
    for (int i = 0; i < 4; ++i)
        swA[i] = (lq ^ ((i * 2 + (lm >> 3)) & 3)) * 8;

    // prologue: tile 0
    uint4 av = ldA_yt(YT, b, l0, 0);
    stage_tile_512(Wo, Ba[0], n0, 0);
    stage_tile_512(Wo, Bg[0], 512 + n0, 0);
    dswA(As[0], av);
    __syncthreads();

    int cur = 0;
    for (int k0 = 32; k0 < 512; k0 += 32) {
        const int nx = cur ^ 1;
        uint4 avn = ldA_yt(YT, b, l0, k0);            // issue early (T14)
        stage_tile_512(Wo, Ba[nx], n0, k0);
        stage_tile_512(Wo, Bg[nx], 512 + n0, k0);

        bf16x8 af[4], ba[2], bg[2];
        #pragma unroll
        for (int i = 0; i < 4; ++i)
            af[i] = *(const bf16x8*)&As[cur][(wm * 64 + i * 16 + lm) * 32 + swA[i]];
        #pragma unroll
        for (int j = 0; j < 2; ++j) {
            ba[j] = *(const bf16x8*)&Ba[cur][(wn * 32 + j * 16 + lm) * 32 + sw];
            bg[j] = *(const bf16x8*)&Bg[cur][(wn * 32 + j * 16 + lm) * 32 + sw];
        }
        #pragma unroll
        for (int i = 0; i < 4; ++i) {
            #pragma unroll
            for (int j = 0; j < 2; ++j) {
                accA[i][j] = __builtin_amdgcn_mfma_f32_16x16x32_bf16(af[i], ba[j], accA[i][j], 0, 0, 0);
                accG[i][j] = __builtin_amdgcn_mfma_f32_16x16x32_bf16(af[i], bg[j], accG[i][j], 0, 0, 0);
            }
        }
        dswA(As[nx], avn);                            // write late, under MFMA-covered latency
        __syncthreads();
        cur = nx;
    }
    // final K-tile (no prefetch)
    {
        bf16x8 af[4], ba[2], bg[2];
        #pragma unroll
        for (int i = 0; i < 4; ++i)
            af[i] = *(const bf16x8*)&As[cur][(wm * 64 + i * 16 + lm) * 32 + swA[i]];
        #pragma unroll
        for (int j = 0; j < 2; ++j) {
            ba[j] = *(const bf16x8*)&Ba[cur][(wn * 32 + j * 16 + lm) * 32 + sw];
            bg[j] = *(const bf16x8*)&Bg[cur][(wn * 32 + j * 16 + lm) * 32 + sw];
        }
        #pragma unroll
        for (int i = 0; i < 4; ++i) {
            #pragma unroll
            for (int j = 0; j < 2; ++j) {
                accA[i][j] = __builtin_amdgcn_mfma_f32_16x16x32_bf16(af[i], ba[j], accA[i][j], 0, 0, 0);
                accG[i][j] = __builtin_amdgcn_mfma_f32_16x16x32_bf16(af[i], bg[j], accG[i][j], 0, 0, 0);
            }
        }
    }

    // epilogue: GLU + residual, accumulate LN1 row partials
    float bav[2], bgv[2];
    #pragma unroll
    for (int j = 0; j < 2; ++j) {
        int n = n0 + wn * 32 + j * 16 + lm;
        bav[j] = bo[n]; bgv[j] = bo[512 + n];
    }
    #pragma unroll
    for (int i = 0; i < 4; ++i) {
        #pragma unroll
        for (int r = 0; r < 4; ++r) {
            int row = wm * 64 + i * 16 + lq * 4 + r;
            int m = m0 + row;
            float s = 0.0f, sq = 0.0f;
            #pragma unroll
            for (int j = 0; j < 2; ++j) {
                int n = n0 + wn * 32 + j * 16 + lm;
                float a_ = accA[i][j][r] + bav[j];
                float g_ = accG[i][j][r] + bgv[j];
                float xv = x[(size_t)m * 512 + n];
                float ov = fmaf(a_, sigmoidf_(g_), xv);
                out[(size_t)m * 512 + n] = f2b(ov);
                s += ov; sq = fmaf(ov, ov, sq);
            }
            #pragma unroll
            for (int msk = 1; msk < 16; msk <<= 1) {
                s  += __shfl_xor(s, msk, 64);
                sq += __shfl_xor(sq, msk, 64);
            }
            if (lm == 0) { float2 p; p.x = s; p.y = sq; red1[row][wn] = p; }
        }
    }
    __syncthreads();
    if (t < 128) {
        float s = 0.0f, sq = 0.0f;
        #pragma unroll
        for (int w = 0; w < 4; ++w) { float2 p = red1[t][w]; s += p.x; sq += p.y; }
        float2 o; o.x = s; o.y = sq;
        Pstats[(size_t)(m0 + t) * 4 + blockIdx.y] = o;
    }
}

// ---------------------------------------------------------------------------
// 6) GEMM (W1*g1 folded) + LN1 epilogue + ReLU:
//    h1 = relu( rs_m*(W1g·z)[f] - rs_m*mu_m*c1[f] + c2[f] + bc1[f] )
//    Structure identical to proven gemm kernel; only epilogue differs.
// ---------------------------------------------------------------------------
__global__ __launch_bounds__(512) void gemm_relu_kernel(
    const u16* __restrict__ A, const u16* __restrict__ Bw,
    const float* __restrict__ bias, const float2* __restrict__ Pstats,
    const float* __restrict__ c1, const float* __restrict__ c2,
    u16* __restrict__ C)
{
    __shared__ u16 As[2][128 * 32];
    __shared__ u16 Bs[2][128 * 32];
    __shared__ float musig[128][2];
    const int t    = threadIdx.x;
    const int lane = t & 63;
    const int wv   = t >> 6;
    const int wm   = wv >> 2, wn = wv & 3;
    const int lm   = lane & 15, lq = lane >> 4;
    const int sw   = (lq ^ ((lm >> 1) & 3)) * 8;
    const int m0   = blockIdx.x * 128, n0 = blockIdx.y * 128;
    floatx4 acc[4][2] = {};

    if (t < 128) {
        float s = 0.0f, sq = 0.0f;
        #pragma unroll
        for (int w = 0; w < 4; ++w) {
            float2 p = Pstats[(size_t)(m0 + t) * 4 + w];
            s += p.x; sq += p.y;
        }
        float mu  = s * (1.0f / 512.0f);
        float var = sq * (1.0f / 512.0f) - mu * mu;
        musig[t][0] = mu;
        musig[t][1] = rsqrtf(var + 1e-5f);
    }
    stage_tile_512(A, As[0], m0, 0);
    stage_tile_512(Bw, Bs[0], n0, 0);
    __syncthreads();

    int cur = 0;
    for (int k0 = 32; k0 < 512; k0 += 32) {
        const int nx = cur ^ 1;
        stage_tile_512(A, As[nx], m0, k0);
        stage_tile_512(Bw, Bs[nx], n0, k0);

        bf16x8 af[4], bfr[2];
        #pragma unroll
        for (int i = 0; i < 4; ++i)
            af[i] = *(const bf16x8*)&As[cur][(wm * 64 + i * 16 + lm) * 32 + sw];
        #pragma unroll
        for (int j = 0; j < 2; ++j)
            bfr[j] = *(const bf16x8*)&Bs[cur][(wn * 32 + j * 16 + lm) * 32 + sw];
        #pragma unroll
        for (int i = 0; i < 4; ++i) {
            #pragma unroll
            for (int j = 0; j < 2; ++j)
                acc[i][j] = __builtin_amdgcn_mfma_f32_16x16x32_bf16(af[i], bfr[j], acc[i][j], 0, 0, 0);
        }
        __syncthreads();
        cur = nx;
    }
    {
        bf16x8 af[4], bfr[2];
        #pragma unroll
        for (int i = 0; i < 4; ++i)
            af[i] = *(const bf16x8*)&As[cur][(wm * 64 + i * 16 + lm) * 32 + sw];
        #pragma unroll
        for (int j = 0; j < 2; ++j)
            bfr[j] = *(const bf16x8*)&Bs[cur][(wn * 32 + j * 16 + lm) * 32 + sw];
        #pragma unroll
        for (int i = 0; i < 4; ++i) {
            #pragma unroll
            for (int j = 0; j < 2; ++j)
                acc[i][j] = __builtin_amdgcn_mfma_f32_16x16x32_bf16(af[i], bfr[j], acc[i][j], 0, 0, 0);
        }
    }
    float c1v[2], c2v[2];
    #pragma unroll
    for (int j = 0; j < 2; ++j) {
        int n = n0 + wn * 32 + j * 16 + lm;
        c1v[j] = c1[n];
        c2v[j] = c2[n] + bias[n];
    }
    #pragma unroll
    for (int i = 0; i < 4; ++i) {
        #pragma unroll
        for (int r = 0; r < 4; ++r) {
            int row = wm * 64 + i * 16 + lq * 4 + r;
            float mu = musig[row][0], rs = musig[row][1];
            float nmr = -rs * mu;
            #pragma unroll
            for (int j = 0; j < 2; ++j) {
                int n = n0 + wn * 32 + j * 16 + lm;
                float v = fmaf(rs, acc[i][j][r], fmaf(nmr, c1v[j], c2v[j]));
                C[(size_t)(m0 + row) * 512 + n] = f2b(fmaxf(v, 0.0f));
            }
        }
    }
}

// ---------------------------------------------------------------------------
// 7) FUSED GEMM2 + LN1'd residual + LayerNorm2 -> fp32 out.
//    Residual x_ln re-materialized from x1pre + stats (LN1 never stored).
// ---------------------------------------------------------------------------
__global__ __launch_bounds__(512) void gemm2_ln_kernel(
    const u16* __restrict__ A, const u16* __restrict__ Bw,
    const float* __restrict__ bias, const u16* __restrict__ res,
    const float2* __restrict__ Pstats,
    const float* __restrict__ g1, const float* __restrict__ beta1,
    const float* __restrict__ gamma, const float* __restrict__ beta,
    float* __restrict__ out)
{
    __shared__ u16 As[2][32 * 32];
    __shared__ u16 Bs[2][512 * 32];
    __shared__ float2 lnred[32 * 8];
    __shared__ float musig2[32][2];
    const int t    = threadIdx.x;
    const int lane = t & 63;
    const int wv   = t >> 6;
    const int lm   = lane & 15, lq = lane >> 4;
    const int sw   = (lq ^ ((lm >> 1) & 3)) * 8;
    const int m0   = blockIdx.x * 32;
    floatx4 acc[2][4] = {};

    const int csrc = (t & 3) ^ ((t >> 3) & 3);

    if (t < 32) {
        float s = 0.0f, sq = 0.0f;
        #pragma unroll
        for (int w = 0; w < 4; ++w) {
            float2 p = Pstats[(size_t)(m0 + t) * 4 + w];
            s += p.x; sq += p.y;
        }
        float mu  = s * (1.0f / 512.0f);
        float var = sq * (1.0f / 512.0f) - mu * mu;
        musig2[t][0] = mu;
        musig2[t][1] = rsqrtf(var + 1e-5f);
    }
    // prologue stage k=0
    {
        #pragma unroll
        for (int r = 0; r < 4; ++r) {
            int row = (t >> 2) + r * 128;
            const u16* gp = Bw + (size_t)row * 512 + csrc * 8;
            __builtin_amdgcn_global_load_lds(
                (const __attribute__((address_space(1))) unsigned int*)gp,
                (__attribute__((address_space(3))) unsigned int*)(&Bs[0][0] + (size_t)t * 8 + (size_t)r * 4096),
                16, 0, 0);
        }
        if (t < 128) {
            int row = t >> 2;
            const u16* gp = A + (size_t)(m0 + row) * 512 + csrc * 8;
            __builtin_amdgcn_global_load_lds(
                (const __attribute__((address_space(1))) unsigned int*)gp,
                (__attribute__((address_space(3))) unsigned int*)(&As[0][0] + (size_t)t * 8),
                16, 0, 0);
        }
    }
    __syncthreads();

    int cur = 0;
    for (int k0 = 32; k0 < 512; k0 += 32) {
        const int nx = cur ^ 1;
        #pragma unroll
        for (int r = 0; r < 4; ++r) {
            int row = (t >> 2) + r * 128;
            const u16* gp = Bw + (size_t)row * 512 + k0 + csrc * 8;
            __builtin_amdgcn_global_load_lds(
                (const __attribute__((address_space(1))) unsigned int*)gp,
                (__attribute__((address_space(3))) unsigned int*)(&Bs[nx][0] + (size_t)t * 8 + (size_t)r * 4096),
                16, 0, 0);
        }
        if (t < 128) {
            int row = t >> 2;
            const u16* gp = A + (size_t)(m0 + row) * 512 + k0 + csrc * 8;
            __builtin_amdgcn_global_load_lds(
                (const __attribute__((address_space(1))) unsigned int*)gp,
                (__attribute__((address_space(3))) unsigned int*)(&As[nx][0] + (size_t)t * 8),
                16, 0, 0);
        }

        bf16x8 af[2], bfr[4];
        #pragma unroll
        for (int i = 0; i < 2; ++i)
            af[i] = *(const bf16x8*)&As[cur][(i * 16 + lm) * 32 + sw];
        #pragma unroll
        for (int j = 0; j < 4; ++j)
            bfr[j] = *(const bf16x8*)&Bs[cur][(wv * 64 + j * 16 + lm) * 32 + sw];
        #pragma unroll
        for (int i = 0; i < 2; ++i) {
            #pragma unroll
            for (int j = 0; j < 4; ++j)
                acc[i][j] = __builtin_amdgcn_mfma_f32_16x16x32_bf16(af[i], bfr[j], acc[i][j], 0, 0, 0);
        }
        __syncthreads();
        cur = nx;
    }
    {
        bf16x8 af[2], bfr[4];
        #pragma unroll
        for (int i = 0; i < 2; ++i)
            af[i] = *(const bf16x8*)&As[cur][(i * 16 + lm) * 32 + sw];
        #pragma unroll
        for (int j = 0; j < 4; ++j)
            bfr[j] = *(const bf16x8*)&Bs[cur][(wv * 64 + j * 16 + lm) * 32 + sw];
        #pragma unroll
        for (int i = 0; i < 2; ++i) {
            #pragma unroll
            for (int j = 0; j < 4; ++j)
                acc[i][j] = __builtin_amdgcn_mfma_f32_16x16x32_bf16(af[i], bfr[j], acc[i][j], 0, 0, 0);
        }
    }

    // epilogue: z = acc + bias + LN1(res); then rowwise LN2 over N=512
    float bv[4], gv1[4], bt1[4], gv[4], btv[4];
    #pragma unroll
    for (int j = 0; j < 4; ++j) {
        int n = wv * 64 + j * 16 + lm;
        bv[j]  = bias[n];
        gv1[j] = g1[n];
        bt1[j] = beta1[n];
        gv[j]  = gamma[n];
        btv[j] = beta[n];
    }
    #pragma unroll
    for (int i = 0; i < 2; ++i) {
        #pragma unroll
        for (int r = 0; r < 4; ++r) {
            int row = i * 16 + lq * 4 + r;
            float mu1 = musig2[row][0], rs1 = musig2[row][1];
            int m = m0 + row;
            #pragma unroll
            for (int j = 0; j < 4; ++j) {
                int n = wv * 64 + j * 16 + lm;
                float zl = fmaf((b2f(res[(size_t)m * 512 + n]) - mu1) * rs1, gv1[j], bt1[j]);
                acc[i][j][r] += bv[j] + zl;
            }
        }
    }
    #pragma unroll
    for (int i = 0; i < 2; ++i) {
        #pragma unroll
        for (int r = 0; r < 4; ++r) {
            float s  = acc[i][0][r] + acc[i][1][r] + acc[i][2][r] + acc[i][3][r];
            float sq = acc[i][0][r] * acc[i][0][r] + acc[i][1][r] * acc[i][1][r]
                     + acc[i][2][r] * acc[i][2][r] + acc[i][3][r] * acc[i][3][r];
            #pragma unroll
            for (int msk = 1; msk < 16; msk <<= 1) {
                s  += __shfl_xor(s, msk, 64);
                sq += __shfl_xor(sq, msk, 64);
            }
            if (lm == 0) {
                float2 p; p.x = s; p.y = sq;
                lnred[(i * 16 + lq * 4 + r) * 8 + wv] = p;
            }
        }
    }
    __syncthreads();
    #pragma unroll
    for (int i = 0; i < 2; ++i) {
        #pragma unroll
        for (int r = 0; r < 4; ++r) {
            int row = i * 16 + lq * 4 + r;
            float s = 0.0f, sq = 0.0f;
            #pragma unroll
            for (int w = 0; w < 8; ++w) {
                float2 p = lnred[row * 8 + w];
                s += p.x; sq += p.y;
            }
            float mu  = s * (1.0f / 512.0f);
            float var = sq * (1.0f / 512.0f) - mu * mu;
            float rs  = rsqrtf(var + 1e-5f);
            #pragma unroll
            for (int j = 0; j < 4; ++j) {
                int n = wv * 64 + j * 16 + lm;
                out[(size_t)(m0 + row) * 512 + n] = fmaf((acc[i][j][r] - mu) * rs, gv[j], btv[j]);
            }
        }
    }
}

// ---------------------------------------------------------------------------
extern "C" void kernel_launch(void* const* d_in, const int* in_sizes, int n_in,
                              void* d_out, int out_size, void* d_ws, size_t ws_size,
                              hipStream_t stream)
{
    (void)in_sizes; (void)n_in; (void)out_size; (void)ws_size;
    const float* x      = (const float*)d_in[0];
    const float* log_dt = (const float*)d_in[1];
    const float* A_re   = (const float*)d_in[2];
    const float* A_im   = (const float*)d_in[3];
    const float* C_re   = (const float*)d_in[4];
    const float* C_im   = (const float*)d_in[5];
    const float* D_skip = (const float*)d_in[6];
    const float* W_out  = (const float*)d_in[7];
    const float* b_out  = (const float*)d_in[8];
    const float* g1     = (const float*)d_in[9];
    const float* beta1  = (const float*)d_in[10];
    const float* g2     = (const float*)d_in[11];
    const float* beta2  = (const float*)d_in[12];
    const float* W1     = (const float*)d_in[13];
    const float* bc1    = (const float*)d_in[14];
    const float* W2     = (const float*)d_in[15];
    const float* bc2    = (const float*)d_in[16];
    float* out = (float*)d_out;

    // workspace: P 512K | hole | Toep 4M | weights 2M | r1/r2/r3 | Pstats | c1 c2
    char*   wsb    = (char*)d_ws;
    float*  P      = (float*)wsb;
    u16*    Toep   = (u16*)(wsb + 4 * HN * 4 + 512 * 64 * 4);
    u16*    Wobf   = Toep + 512 * 4096;
    u16*    W1bf   = Wobf + 1024 * 512;
    u16*    W2bf   = W1bf + 512 * 512;
    u16*    r1     = W2bf + 512 * 512;   // XT -> h1_bf
    u16*    r2     = r1 + BLH;           // YT
    u16*    r3     = r2 + BLH;           // x1pre_bf
    float2* Pstats = (float2*)(r3 + BLH);
    float*  c1     = (float*)(Pstats + (size_t)M_DIM * 4);
    float*  c2     = c1 + 512;

    setup_kernel<<<9472, 256, 0, stream>>>(x, W_out, W1, W2, log_dt, A_re, A_im,
                                           C_re, C_im, g1, beta1,
                                           r1, Wobf, W1bf, W2bf, P, Toep, c1, c2);
    ssm_chunk_kernel<<<dim3(H_DIM, 2), 256, 0, stream>>>(r1, P, Toep, D_skip, r2);
    gemm1_glu_kernel<<<dim3(M_DIM / 128, 4), 512, 0, stream>>>(r2, Wobf, b_out, x, r3, Pstats);
    gemm_relu_kernel<<<dim3(M_DIM / 128, 4), 512, 0, stream>>>(r3, W1bf, bc1, Pstats, c1, c2, r1);
    gemm2_ln_kernel<<<M_DIM / 32, 512, 0, stream>>>(r1, W2bf, bc2, r3, Pstats, g1, beta1, g2, beta2, out);
}